// Round 1
// baseline (1104.294 us; speedup 1.0000x reference)
//
#include <hip/hip_runtime.h>

#define NN 100000
#define NE 1600000
#define D  128
#define BN_EPS 1e-5f
#define RPB 32   // rows per block in GEMM

// ---------------- Kernel 1: degree counts ----------------
__global__ void k_deg(const int* __restrict__ src, const int* __restrict__ dst,
                      float* __restrict__ degout, float* __restrict__ degin) {
    int e = blockIdx.x * blockDim.x + threadIdx.x;
    if (e < NE) {
        atomicAdd(&degout[src[e]], 1.0f);
        atomicAdd(&degin[dst[e]], 1.0f);
    }
}

// ---------------- Kernel 2: h = (x * rsqrt(max(deg_out,1))) @ W ----------------
__global__ __launch_bounds__(256) void k_gemm(const float* __restrict__ x,
                                              const float* __restrict__ degout,
                                              const float* __restrict__ W,
                                              float* __restrict__ h) {
    __shared__ float Wl[D * D];       // 64 KB
    __shared__ float xl[RPB][D];      // 16 KB
    __shared__ float nrm[RPB];

    const int t = threadIdx.x;
    const int base = blockIdx.x * RPB;

    for (int i = t; i < D * D; i += 256) Wl[i] = W[i];
    if (t < RPB) nrm[t] = rsqrtf(fmaxf(degout[base + t], 1.0f));
    __syncthreads();
    for (int i = t; i < RPB * D; i += 256) {
        int r = i >> 7, k = i & 127;
        xl[r][k] = x[(size_t)(base + r) * D + k] * nrm[r];
    }
    __syncthreads();

    const int c  = t & 127;   // output column
    const int rp = t >> 7;    // row parity (0/1)

    float acc[16];
#pragma unroll
    for (int i = 0; i < 16; ++i) acc[i] = 0.0f;

    for (int k = 0; k < D; ++k) {
        float w = Wl[k * D + c];
#pragma unroll
        for (int i = 0; i < 16; ++i)
            acc[i] += xl[rp + 2 * i][k] * w;
    }
#pragma unroll
    for (int i = 0; i < 16; ++i)
        h[(size_t)(base + rp + 2 * i) * D + c] = acc[i];
}

// ---------------- Kernel 3: agg[dst] += h[src]  (element-parallel atomics) ----------------
__global__ void k_scatter(const float* __restrict__ h, const int* __restrict__ src,
                          const int* __restrict__ dst, float* __restrict__ agg) {
    const long total = (long)NE * D;
    long i = (long)blockIdx.x * blockDim.x + threadIdx.x;
    const long stride = (long)gridDim.x * blockDim.x;
    for (; i < total; i += stride) {
        int e = (int)(i >> 7);
        int c = (int)(i & 127);
        float v = h[(size_t)src[e] * D + c];
        atomicAdd(&agg[(size_t)dst[e] * D + c], v);
    }
}

// ---------------- Kernel 4: column sums / sumsq of h2 = agg*norm_dst + b ----------------
__global__ __launch_bounds__(256) void k_stats(const float* __restrict__ agg,
                                               const float* __restrict__ degin,
                                               const float* __restrict__ b,
                                               float* __restrict__ stats) {
    __shared__ float sh1[256], sh2[256];
    const int t = threadIdx.x;
    const int c = t & 127;
    const float bc = b[c];
    float s1 = 0.0f, s2 = 0.0f;
    const long total = (long)NN * D;
    const long stride = (long)gridDim.x * 256;
    for (long i = (long)blockIdx.x * 256 + t; i < total; i += stride) {
        int r = (int)(i >> 7);
        float v = agg[i] * rsqrtf(fmaxf(degin[r], 1.0f)) + bc;
        s1 += v;
        s2 += v * v;
    }
    sh1[t] = s1; sh2[t] = s2;
    __syncthreads();
    if (t < 128) {
        atomicAdd(&stats[c],       sh1[t] + sh1[t + 128]);
        atomicAdd(&stats[128 + c], sh2[t] + sh2[t + 128]);
    }
}

// ---------------- Kernel 5: BN + ReLU + residual ----------------
__global__ void k_final(const float* __restrict__ agg, const float* __restrict__ degin,
                        const float* __restrict__ x, const float* __restrict__ b,
                        const float* __restrict__ gamma, const float* __restrict__ beta,
                        const float* __restrict__ stats, float* __restrict__ out) {
    long i = (long)blockIdx.x * blockDim.x + threadIdx.x;
    const long total = (long)NN * D;
    if (i >= total) return;
    int r = (int)(i >> 7);
    int c = (int)(i & 127);
    const float inv_n = 1.0f / (float)NN;
    float mean = stats[c] * inv_n;
    float var  = stats[128 + c] * inv_n - mean * mean;
    float v = agg[i] * rsqrtf(fmaxf(degin[r], 1.0f)) + b[c];
    v = (v - mean) * rsqrtf(var + BN_EPS) * gamma[c] + beta[c];
    v = fmaxf(v, 0.0f);
    out[i] = v + x[i];
}

extern "C" void kernel_launch(void* const* d_in, const int* in_sizes, int n_in,
                              void* d_out, int out_size, void* d_ws, size_t ws_size,
                              hipStream_t stream) {
    const float* x     = (const float*)d_in[0];
    const int*   src   = (const int*)d_in[1];
    const int*   dst   = (const int*)d_in[2];
    const float* W     = (const float*)d_in[3];
    const float* b     = (const float*)d_in[4];
    const float* gamma = (const float*)d_in[5];
    const float* beta  = (const float*)d_in[6];
    float* out = (float*)d_out;

    float* ws     = (float*)d_ws;
    float* agg    = ws;                         // NN*D floats
    float* degout = ws + (size_t)NN * D;        // NN
    float* degin  = degout + NN;                // NN
    float* stats  = degin + NN;                 // 256

    // h uses d_out as scratch (overwritten by k_final at the end)
    float* h = out;

    const size_t zero_bytes = ((size_t)NN * D + 2 * NN + 256) * sizeof(float);
    hipMemsetAsync(d_ws, 0, zero_bytes, stream);

    k_deg<<<(NE + 255) / 256, 256, 0, stream>>>(src, dst, degout, degin);
    k_gemm<<<NN / RPB, 256, 0, stream>>>(x, degout, W, h);
    k_scatter<<<2048, 256, 0, stream>>>(h, src, dst, agg);
    k_stats<<<1024, 256, 0, stream>>>(agg, degin, b, stats);
    k_final<<<((long)NN * D + 255) / 256, 256, 0, stream>>>(agg, degin, x, b, gamma, beta, stats, out);
}

// Round 2
// 870.217 us; speedup vs baseline: 1.2690x; 1.2690x over previous
//
#include <hip/hip_runtime.h>

#define NN 100000
#define NE 1600000
#define D  128
#define BN_EPS 1e-5f
#define RPB 32   // rows per block in GEMM

// ---------------- Kernel 1: degree counts ----------------
__global__ void k_deg(const int* __restrict__ src, const int* __restrict__ dst,
                      float* __restrict__ degout, float* __restrict__ degin) {
    int e = blockIdx.x * blockDim.x + threadIdx.x;
    if (e < NE) {
        atomicAdd(&degout[src[e]], 1.0f);
        atomicAdd(&degin[dst[e]], 1.0f);
    }
}

// ---------------- Kernel 2: h = (x * rsqrt(max(deg_out,1))) @ W ----------------
__global__ __launch_bounds__(256) void k_gemm(const float* __restrict__ x,
                                              const float* __restrict__ degout,
                                              const float* __restrict__ W,
                                              float* __restrict__ h) {
    __shared__ float Wl[D * D];       // 64 KB
    __shared__ float xl[RPB][D];      // 16 KB
    __shared__ float nrm[RPB];

    const int t = threadIdx.x;
    const int base = blockIdx.x * RPB;

    for (int i = t; i < D * D; i += 256) Wl[i] = W[i];
    if (t < RPB) nrm[t] = rsqrtf(fmaxf(degout[base + t], 1.0f));
    __syncthreads();
    for (int i = t; i < RPB * D; i += 256) {
        int r = i >> 7, k = i & 127;
        xl[r][k] = x[(size_t)(base + r) * D + k] * nrm[r];
    }
    __syncthreads();

    const int c  = t & 127;   // output column
    const int rp = t >> 7;    // row parity (0/1)

    float acc[16];
#pragma unroll
    for (int i = 0; i < 16; ++i) acc[i] = 0.0f;

    for (int k = 0; k < D; ++k) {
        float w = Wl[k * D + c];
#pragma unroll
        for (int i = 0; i < 16; ++i)
            acc[i] += xl[rp + 2 * i][k] * w;
    }
#pragma unroll
    for (int i = 0; i < 16; ++i)
        h[(size_t)(base + rp + 2 * i) * D + c] = acc[i];
}

// ---------------- Kernel 3a: exclusive scan of degin -> ptr[NN+1] ----------------
__global__ __launch_bounds__(1024) void k_scan(const float* __restrict__ degin,
                                               int* __restrict__ ptr) {
    __shared__ int part[1024];
    const int t = threadIdx.x;
    const int CH = (NN + 1023) / 1024;   // 98
    const int begin = t * CH;
    const int end = (begin + CH < NN) ? begin + CH : NN;
    int s = 0;
    for (int i = begin; i < end; ++i) s += (int)degin[i];
    part[t] = s;
    __syncthreads();
    // Hillis-Steele inclusive scan in LDS
    for (int off = 1; off < 1024; off <<= 1) {
        int v = (t >= off) ? part[t - off] : 0;
        __syncthreads();
        part[t] += v;
        __syncthreads();
    }
    int run = (t == 0) ? 0 : part[t - 1];
    for (int i = begin; i < end; ++i) {
        ptr[i] = run;
        run += (int)degin[i];
    }
    if (t == 1023) ptr[NN] = part[1023];
}

// ---------------- Kernel 3b: fill CSR edge array (src ids grouped by dst) ----------------
__global__ void k_fill(const int* __restrict__ src, const int* __restrict__ dst,
                       const int* __restrict__ ptr, int* __restrict__ cursor,
                       int* __restrict__ esrc) {
    int e = blockIdx.x * blockDim.x + threadIdx.x;
    if (e < NE) {
        int d = dst[e];
        int p = atomicAdd(&cursor[d], 1);
        esrc[ptr[d] + p] = src[e];
    }
}

// ---------------- Kernel 3c: per-node gather-sum, fused *norm_dst + b ----------------
__global__ __launch_bounds__(256) void k_agg(const float* __restrict__ h,
                                             const int* __restrict__ ptr,
                                             const int* __restrict__ esrc,
                                             const float* __restrict__ degin,
                                             const float* __restrict__ b,
                                             float* __restrict__ h2) {
    const int node = blockIdx.x * 2 + (threadIdx.x >> 7);
    const int c = threadIdx.x & 127;
    if (node >= NN) return;
    const int s0 = ptr[node];
    const int s1 = ptr[node + 1];
    float acc0 = 0.0f, acc1 = 0.0f;
    int i = s0;
    for (; i + 1 < s1; i += 2) {
        int e0 = esrc[i], e1 = esrc[i + 1];
        acc0 += h[(size_t)e0 * D + c];
        acc1 += h[(size_t)e1 * D + c];
    }
    if (i < s1) acc0 += h[(size_t)esrc[i] * D + c];
    float v = (acc0 + acc1) * rsqrtf(fmaxf(degin[node], 1.0f)) + b[c];
    h2[(size_t)node * D + c] = v;
}

// ---------------- Kernel 4: column sums / sumsq of h2 ----------------
__global__ __launch_bounds__(256) void k_stats(const float* __restrict__ h2,
                                               float* __restrict__ stats) {
    __shared__ float sh1[256], sh2[256];
    const int t = threadIdx.x;
    const int c = t & 127;
    float s1 = 0.0f, s2 = 0.0f;
    const long total = (long)NN * D;
    const long stride = (long)gridDim.x * 256;
    for (long i = (long)blockIdx.x * 256 + t; i < total; i += stride) {
        float v = h2[i];
        s1 += v;
        s2 += v * v;
    }
    sh1[t] = s1; sh2[t] = s2;
    __syncthreads();
    if (t < 128) {
        atomicAdd(&stats[c],       sh1[t] + sh1[t + 128]);
        atomicAdd(&stats[128 + c], sh2[t] + sh2[t + 128]);
    }
}

// ---------------- Kernel 5: BN + ReLU + residual ----------------
__global__ void k_final(const float* __restrict__ h2, const float* __restrict__ x,
                        const float* __restrict__ gamma, const float* __restrict__ beta,
                        const float* __restrict__ stats, float* __restrict__ out) {
    long i = (long)blockIdx.x * blockDim.x + threadIdx.x;
    const long total = (long)NN * D;
    if (i >= total) return;
    int c = (int)(i & 127);
    const float inv_n = 1.0f / (float)NN;
    float mean = stats[c] * inv_n;
    float var  = stats[128 + c] * inv_n - mean * mean;
    float v = h2[i];
    v = (v - mean) * rsqrtf(var + BN_EPS) * gamma[c] + beta[c];
    v = fmaxf(v, 0.0f);
    out[i] = v + x[i];
}

extern "C" void kernel_launch(void* const* d_in, const int* in_sizes, int n_in,
                              void* d_out, int out_size, void* d_ws, size_t ws_size,
                              hipStream_t stream) {
    const float* x     = (const float*)d_in[0];
    const int*   src   = (const int*)d_in[1];
    const int*   dst   = (const int*)d_in[2];
    const float* W     = (const float*)d_in[3];
    const float* b     = (const float*)d_in[4];
    const float* gamma = (const float*)d_in[5];
    const float* beta  = (const float*)d_in[6];
    float* out = (float*)d_out;

    // Workspace layout
    float* ws     = (float*)d_ws;
    float* h2     = ws;                               // NN*D floats (fully overwritten)
    float* degout = ws + (size_t)NN * D;              // NN  -- zeroed
    float* degin  = degout + NN;                      // NN  -- zeroed
    int*   cursor = (int*)(degin + NN);               // NN  -- zeroed
    float* stats  = (float*)(cursor + NN);            // 256 -- zeroed
    int*   ptr    = (int*)(stats + 256);              // NN+1
    int*   esrc   = ptr + (NN + 1);                   // NE

    // h uses d_out as scratch (overwritten by k_final at the end)
    float* h = out;

    // zero only degout, degin, cursor, stats (contiguous): ~1.2 MB
    const size_t zero_bytes = ((size_t)3 * NN + 256) * sizeof(float);
    hipMemsetAsync(degout, 0, zero_bytes, stream);

    k_deg<<<(NE + 255) / 256, 256, 0, stream>>>(src, dst, degout, degin);
    k_gemm<<<NN / RPB, 256, 0, stream>>>(x, degout, W, h);
    k_scan<<<1, 1024, 0, stream>>>(degin, ptr);
    k_fill<<<(NE + 255) / 256, 256, 0, stream>>>(src, dst, ptr, cursor, esrc);
    k_agg<<<(NN + 1) / 2, 256, 0, stream>>>(h, ptr, esrc, degin, b, h2);
    k_stats<<<1024, 256, 0, stream>>>(h2, stats);
    k_final<<<((long)NN * D + 255) / 256, 256, 0, stream>>>(h2, x, gamma, beta, stats, out);
}

// Round 3
// 612.912 us; speedup vs baseline: 1.8017x; 1.4198x over previous
//
#include <hip/hip_runtime.h>
#include <hip/hip_bf16.h>

#define NN 100000
#define NE 1600000
#define D  128
#define BN_EPS 1e-5f

typedef __attribute__((ext_vector_type(8))) short bf16x8;
typedef __attribute__((ext_vector_type(4))) float f32x4;

#define WLD 136   // padded row stride (ushorts) for W^T in LDS: 2-way banks only

static __device__ __forceinline__ ushort f2bf(float f) {
    __hip_bfloat16 b = __float2bfloat16(f);
    return *reinterpret_cast<ushort*>(&b);
}
static __device__ __forceinline__ float bflo(unsigned v) {
    return __uint_as_float((v & 0xffffu) << 16);
}
static __device__ __forceinline__ float bfhi(unsigned v) {
    return __uint_as_float(v & 0xffff0000u);
}

// ---------------- Kernel 0: W^T cast to bf16 ----------------
__global__ void k_wcast(const float* __restrict__ W, ushort* __restrict__ WT) {
    int i = blockIdx.x * 256 + threadIdx.x;   // 16384
    int n = i >> 7, k = i & 127;
    WT[i] = f2bf(W[k * D + n]);               // WT[n][k] = W[k][n]
}

// ---------------- Kernel 1: degree counts ----------------
__global__ void k_deg(const int* __restrict__ src, const int* __restrict__ dst,
                      float* __restrict__ degout, float* __restrict__ degin) {
    int e = blockIdx.x * blockDim.x + threadIdx.x;
    if (e < NE) {
        atomicAdd(&degout[src[e]], 1.0f);
        atomicAdd(&degin[dst[e]], 1.0f);
    }
}

// ---------------- Kernel 2: h(bf16) = (x * rsqrt(max(deg_out,1))) @ W via MFMA ----------------
__global__ __launch_bounds__(256) void k_gemm(const float* __restrict__ x,
                                              const float* __restrict__ degout,
                                              const ushort* __restrict__ WT,
                                              ushort* __restrict__ h) {
    __shared__ ushort Wl[D * WLD];   // 34.8 KB

    const int t = threadIdx.x;
    // stage W^T (bf16) into LDS, 16B chunks; 2048 slots, 8 per thread
    for (int s = t; s < 2048; s += 256) {
        int row = s >> 4, slot = s & 15;
        uint4 v = *reinterpret_cast<const uint4*>(WT + row * D + slot * 8);
        *reinterpret_cast<uint4*>(&Wl[row * WLD + slot * 8]) = v;
    }
    __syncthreads();

    const int wave = t >> 6;
    const int lane = t & 63;
    const int m16  = lane & 15;     // row within 16x16 tile (A), col (B/D)
    const int kq   = lane >> 4;     // k-quarter: 8 elems
    const int row  = blockIdx.x * 64 + wave * 16 + m16;
    const int rc   = row < NN ? row : NN - 1;

    const float nrm = rsqrtf(fmaxf(degout[rc], 1.0f));

    // A fragments: lane holds x[rc][kt*32 + kq*8 .. +7] * nrm, bf16
    bf16x8 afrag[4];
    const float* xr = x + (size_t)rc * D + kq * 8;
#pragma unroll
    for (int kt = 0; kt < 4; ++kt) {
        f32x4 lo = *reinterpret_cast<const f32x4*>(xr + kt * 32);
        f32x4 hi = *reinterpret_cast<const f32x4*>(xr + kt * 32 + 4);
        union { bf16x8 v; ushort u[8]; } af;
#pragma unroll
        for (int j = 0; j < 4; ++j) {
            af.u[j]     = f2bf(lo[j] * nrm);
            af.u[4 + j] = f2bf(hi[j] * nrm);
        }
        afrag[kt] = af.v;
    }

    f32x4 acc[8];
#pragma unroll
    for (int nt = 0; nt < 8; ++nt) acc[nt] = (f32x4)(0.0f);

#pragma unroll
    for (int kt = 0; kt < 4; ++kt) {
#pragma unroll
        for (int nt = 0; nt < 8; ++nt) {
            int n = nt * 16 + m16;                               // B col
            const bf16x8 bfrag = *reinterpret_cast<const bf16x8*>(
                &Wl[n * WLD + kt * 32 + kq * 8]);                // B[k..k+7][n] = WT[n][k..]
            acc[nt] = __builtin_amdgcn_mfma_f32_16x16x32_bf16(afrag[kt], bfrag, acc[nt], 0, 0, 0);
        }
    }

    // D layout: col = lane&15, row = (lane>>4)*4 + reg
    const int orow = blockIdx.x * 64 + wave * 16 + kq * 4;
#pragma unroll
    for (int nt = 0; nt < 8; ++nt) {
#pragma unroll
        for (int r = 0; r < 4; ++r) {
            int rr = orow + r;
            if (rr < NN) h[(size_t)rr * D + nt * 16 + m16] = f2bf(acc[nt][r]);
        }
    }
}

// ---------------- Kernel 3a: exclusive scan of degin -> ptr[NN+1] ----------------
__global__ __launch_bounds__(1024) void k_scan(const float* __restrict__ degin,
                                               int* __restrict__ ptr) {
    __shared__ int part[1024];
    const int t = threadIdx.x;
    const int CH = (NN + 1023) / 1024;   // 98
    const int begin = t * CH;
    const int end = (begin + CH < NN) ? begin + CH : NN;
    int s = 0;
    for (int i = begin; i < end; ++i) s += (int)degin[i];
    part[t] = s;
    __syncthreads();
    for (int off = 1; off < 1024; off <<= 1) {
        int v = (t >= off) ? part[t - off] : 0;
        __syncthreads();
        part[t] += v;
        __syncthreads();
    }
    int run = (t == 0) ? 0 : part[t - 1];
    for (int i = begin; i < end; ++i) {
        ptr[i] = run;
        run += (int)degin[i];
    }
    if (t == 1023) ptr[NN] = part[1023];
}

// ---------------- Kernel 3b: fill CSR edge array (src ids grouped by dst) ----------------
__global__ void k_fill(const int* __restrict__ src, const int* __restrict__ dst,
                       const int* __restrict__ ptr, int* __restrict__ cursor,
                       int* __restrict__ esrc) {
    int e = blockIdx.x * blockDim.x + threadIdx.x;
    if (e < NE) {
        int d = dst[e];
        int p = atomicAdd(&cursor[d], 1);
        esrc[ptr[d] + p] = src[e];
    }
}

// ---------------- Kernel 3c: per-node gather-sum of bf16 h, fused *norm_dst + b ----------------
__global__ __launch_bounds__(256) void k_agg(const ushort* __restrict__ h,
                                             const int* __restrict__ ptr,
                                             const int* __restrict__ esrc,
                                             const float* __restrict__ degin,
                                             const float* __restrict__ b,
                                             float* __restrict__ h2) {
    const int node = blockIdx.x * 4 + (threadIdx.x >> 6);
    const int lane = threadIdx.x & 63;
    if (node >= NN) return;
    const int s0 = ptr[node];
    const int s1 = ptr[node + 1];
    float a00 = 0.f, a01 = 0.f, a10 = 0.f, a11 = 0.f;
    int i = s0;
    for (; i + 1 < s1; i += 2) {
        int e0 = esrc[i], e1 = esrc[i + 1];
        unsigned v0 = *reinterpret_cast<const unsigned*>(&h[(size_t)e0 * D + lane * 2]);
        unsigned v1 = *reinterpret_cast<const unsigned*>(&h[(size_t)e1 * D + lane * 2]);
        a00 += bflo(v0); a01 += bfhi(v0);
        a10 += bflo(v1); a11 += bfhi(v1);
    }
    if (i < s1) {
        unsigned v0 = *reinterpret_cast<const unsigned*>(&h[(size_t)esrc[i] * D + lane * 2]);
        a00 += bflo(v0); a01 += bfhi(v0);
    }
    const float nrm = rsqrtf(fmaxf(degin[node], 1.0f));
    float2 o;
    o.x = (a00 + a10) * nrm + b[lane * 2];
    o.y = (a01 + a11) * nrm + b[lane * 2 + 1];
    *reinterpret_cast<float2*>(&h2[(size_t)node * D + lane * 2]) = o;
}

// ---------------- Kernel 4: column sums / sumsq of h2 ----------------
__global__ __launch_bounds__(256) void k_stats(const float* __restrict__ h2,
                                               float* __restrict__ stats) {
    __shared__ float sh1[256], sh2[256];
    const int t = threadIdx.x;
    const int c = t & 127;
    float s1 = 0.0f, s2 = 0.0f;
    const long total = (long)NN * D;
    const long stride = (long)gridDim.x * 256;
    for (long i = (long)blockIdx.x * 256 + t; i < total; i += stride) {
        float v = h2[i];
        s1 += v;
        s2 += v * v;
    }
    sh1[t] = s1; sh2[t] = s2;
    __syncthreads();
    if (t < 128) {
        atomicAdd(&stats[c],       sh1[t] + sh1[t + 128]);
        atomicAdd(&stats[128 + c], sh2[t] + sh2[t + 128]);
    }
}

// ---------------- Kernel 5: BN + ReLU + residual ----------------
__global__ void k_final(const float* __restrict__ h2, const float* __restrict__ x,
                        const float* __restrict__ gamma, const float* __restrict__ beta,
                        const float* __restrict__ stats, float* __restrict__ out) {
    long i = (long)blockIdx.x * blockDim.x + threadIdx.x;
    const long total = (long)NN * D;
    if (i >= total) return;
    int c = (int)(i & 127);
    const float inv_n = 1.0f / (float)NN;
    float mean = stats[c] * inv_n;
    float var  = stats[128 + c] * inv_n - mean * mean;
    float v = h2[i];
    v = (v - mean) * rsqrtf(var + BN_EPS) * gamma[c] + beta[c];
    v = fmaxf(v, 0.0f);
    out[i] = v + x[i];
}

extern "C" void kernel_launch(void* const* d_in, const int* in_sizes, int n_in,
                              void* d_out, int out_size, void* d_ws, size_t ws_size,
                              hipStream_t stream) {
    const float* x     = (const float*)d_in[0];
    const int*   src   = (const int*)d_in[1];
    const int*   dst   = (const int*)d_in[2];
    const float* W     = (const float*)d_in[3];
    const float* b     = (const float*)d_in[4];
    const float* gamma = (const float*)d_in[5];
    const float* beta  = (const float*)d_in[6];
    float* out = (float*)d_out;

    // Workspace layout
    float* ws     = (float*)d_ws;
    float* h2     = ws;                               // NN*D floats (fully overwritten)
    float* degout = ws + (size_t)NN * D;              // NN  -- zeroed
    float* degin  = degout + NN;                      // NN  -- zeroed
    int*   cursor = (int*)(degin + NN);               // NN  -- zeroed
    float* stats  = (float*)(cursor + NN);            // 256 -- zeroed
    int*   ptr    = (int*)(stats + 256);              // NN+1
    int*   esrc   = ptr + (NN + 1);                   // NE
    ushort* WT    = (ushort*)(esrc + NE);             // 128*128 bf16

    // h (bf16) lives in d_out's first half (overwritten by k_final at the end)
    ushort* h = (ushort*)d_out;

    // zero degout, degin, cursor, stats (contiguous): ~1.2 MB
    const size_t zero_bytes = ((size_t)3 * NN + 256) * sizeof(float);
    hipMemsetAsync(degout, 0, zero_bytes, stream);

    k_wcast<<<64, 256, 0, stream>>>(W, WT);
    k_deg<<<(NE + 255) / 256, 256, 0, stream>>>(src, dst, degout, degin);
    k_gemm<<<(NN + 63) / 64, 256, 0, stream>>>(x, degout, WT, h);
    k_scan<<<1, 1024, 0, stream>>>(degin, ptr);
    k_fill<<<(NE + 255) / 256, 256, 0, stream>>>(src, dst, ptr, cursor, esrc);
    k_agg<<<(NN + 3) / 4, 256, 0, stream>>>(h, ptr, esrc, degin, b, h2);
    k_stats<<<1024, 256, 0, stream>>>(h2, stats);
    k_final<<<((long)NN * D + 255) / 256, 256, 0, stream>>>(h2, x, gamma, beta, stats, out);
}

// Round 4
// 462.215 us; speedup vs baseline: 2.3891x; 1.3260x over previous
//
#include <hip/hip_runtime.h>
#include <hip/hip_bf16.h>

#define NN 100000
#define NE 1600000
#define D  128
#define BN_EPS 1e-5f
#define SB 391   // scan blocks = ceil(NN/256)

typedef __attribute__((ext_vector_type(8))) short bf16x8;
typedef __attribute__((ext_vector_type(4))) float f32x4;

#define WLD 136   // padded row stride (ushorts) for W^T in LDS: 2-way banks only

static __device__ __forceinline__ ushort f2bf(float f) {
    __hip_bfloat16 b = __float2bfloat16(f);
    return *reinterpret_cast<ushort*>(&b);
}
static __device__ __forceinline__ float bflo(unsigned v) {
    return __uint_as_float((v & 0xffffu) << 16);
}
static __device__ __forceinline__ float bfhi(unsigned v) {
    return __uint_as_float(v & 0xffff0000u);
}

// ---------------- Kernel 0: W^T cast to bf16 ----------------
__global__ void k_wcast(const float* __restrict__ W, ushort* __restrict__ WT) {
    int i = blockIdx.x * 256 + threadIdx.x;   // 16384
    int n = i >> 7, k = i & 127;
    WT[i] = f2bf(W[k * D + n]);               // WT[n][k] = W[k][n]
}

// ---------------- Kernel 1: degree counts ----------------
__global__ void k_deg(const int* __restrict__ src, const int* __restrict__ dst,
                      float* __restrict__ degout, float* __restrict__ degin) {
    int e = blockIdx.x * blockDim.x + threadIdx.x;
    if (e < NE) {
        atomicAdd(&degout[src[e]], 1.0f);
        atomicAdd(&degin[dst[e]], 1.0f);
    }
}

// ---------------- Kernel 2: h(bf16) = (x * rsqrt(max(deg_out,1))) @ W via MFMA ----------------
__global__ __launch_bounds__(256) void k_gemm(const float* __restrict__ x,
                                              const float* __restrict__ degout,
                                              const ushort* __restrict__ WT,
                                              ushort* __restrict__ h) {
    __shared__ ushort Wl[D * WLD];   // 34.8 KB

    const int t = threadIdx.x;
    for (int s = t; s < 2048; s += 256) {
        int row = s >> 4, slot = s & 15;
        uint4 v = *reinterpret_cast<const uint4*>(WT + row * D + slot * 8);
        *reinterpret_cast<uint4*>(&Wl[row * WLD + slot * 8]) = v;
    }
    __syncthreads();

    const int wave = t >> 6;
    const int lane = t & 63;
    const int m16  = lane & 15;
    const int kq   = lane >> 4;
    const int row  = blockIdx.x * 64 + wave * 16 + m16;
    const int rc   = row < NN ? row : NN - 1;

    const float nrm = rsqrtf(fmaxf(degout[rc], 1.0f));

    bf16x8 afrag[4];
    const float* xr = x + (size_t)rc * D + kq * 8;
#pragma unroll
    for (int kt = 0; kt < 4; ++kt) {
        f32x4 lo = *reinterpret_cast<const f32x4*>(xr + kt * 32);
        f32x4 hi = *reinterpret_cast<const f32x4*>(xr + kt * 32 + 4);
        union { bf16x8 v; ushort u[8]; } af;
#pragma unroll
        for (int j = 0; j < 4; ++j) {
            af.u[j]     = f2bf(lo[j] * nrm);
            af.u[4 + j] = f2bf(hi[j] * nrm);
        }
        afrag[kt] = af.v;
    }

    f32x4 acc[8];
#pragma unroll
    for (int nt = 0; nt < 8; ++nt) acc[nt] = (f32x4)(0.0f);

#pragma unroll
    for (int kt = 0; kt < 4; ++kt) {
#pragma unroll
        for (int nt = 0; nt < 8; ++nt) {
            int n = nt * 16 + m16;
            const bf16x8 bfrag = *reinterpret_cast<const bf16x8*>(
                &Wl[n * WLD + kt * 32 + kq * 8]);
            acc[nt] = __builtin_amdgcn_mfma_f32_16x16x32_bf16(afrag[kt], bfrag, acc[nt], 0, 0, 0);
        }
    }

    const int orow = blockIdx.x * 64 + wave * 16 + kq * 4;
#pragma unroll
    for (int nt = 0; nt < 8; ++nt) {
#pragma unroll
        for (int r = 0; r < 4; ++r) {
            int rr = orow + r;
            if (rr < NN) h[(size_t)rr * D + nt * 16 + m16] = f2bf(acc[nt][r]);
        }
    }
}

// ---------------- Kernel 3a: multi-block exclusive scan of degin -> ptr ----------------
__global__ __launch_bounds__(256) void k_scan1(const float* __restrict__ degin,
                                               int* __restrict__ partial) {
    __shared__ int red[256];
    const int t = threadIdx.x;
    const int i = blockIdx.x * 256 + t;
    red[t] = (i < NN) ? (int)degin[i] : 0;
    __syncthreads();
    for (int off = 128; off > 0; off >>= 1) {
        if (t < off) red[t] += red[t + off];
        __syncthreads();
    }
    if (t == 0) partial[blockIdx.x] = red[0];
}

__global__ __launch_bounds__(512) void k_scan2(int* __restrict__ partial,
                                               int* __restrict__ ptr) {
    __shared__ int sh[512];
    const int t = threadIdx.x;
    sh[t] = (t < SB) ? partial[t] : 0;
    __syncthreads();
    for (int off = 1; off < 512; off <<= 1) {
        int u = (t >= off) ? sh[t - off] : 0;
        __syncthreads();
        sh[t] += u;
        __syncthreads();
    }
    if (t < SB) partial[t] = (t == 0) ? 0 : sh[t - 1];   // exclusive block offsets
    if (t == 511) ptr[NN] = sh[511];                      // total = NE
}

__global__ __launch_bounds__(256) void k_scan3(const float* __restrict__ degin,
                                               const int* __restrict__ partial,
                                               int* __restrict__ ptr) {
    __shared__ int sh[256];
    const int t = threadIdx.x;
    const int i = blockIdx.x * 256 + t;
    const int v = (i < NN) ? (int)degin[i] : 0;
    sh[t] = v;
    __syncthreads();
    for (int off = 1; off < 256; off <<= 1) {
        int u = (t >= off) ? sh[t - off] : 0;
        __syncthreads();
        sh[t] += u;
        __syncthreads();
    }
    if (i < NN) ptr[i] = partial[blockIdx.x] + sh[t] - v;  // exclusive prefix
}

// ---------------- Kernel 3b: fill CSR edge array (src ids grouped by dst) ----------------
__global__ void k_fill(const int* __restrict__ src, const int* __restrict__ dst,
                       const int* __restrict__ ptr, int* __restrict__ cursor,
                       int* __restrict__ esrc) {
    int e = blockIdx.x * blockDim.x + threadIdx.x;
    if (e < NE) {
        int d = dst[e];
        int p = atomicAdd(&cursor[d], 1);
        esrc[ptr[d] + p] = src[e];
    }
}

// ---------------- Kernel 3c: per-node gather-sum of bf16 h, fused *norm_dst + b ----------------
__global__ __launch_bounds__(256) void k_agg(const ushort* __restrict__ h,
                                             const int* __restrict__ ptr,
                                             const int* __restrict__ esrc,
                                             const float* __restrict__ degin,
                                             const float* __restrict__ b,
                                             float* __restrict__ h2) {
    const int node = blockIdx.x * 4 + (threadIdx.x >> 6);
    const int lane = threadIdx.x & 63;
    if (node >= NN) return;
    const int s0 = ptr[node];
    const int s1 = ptr[node + 1];
    float a00 = 0.f, a01 = 0.f, a10 = 0.f, a11 = 0.f;
    int i = s0;
    for (; i + 1 < s1; i += 2) {
        int e0 = esrc[i], e1 = esrc[i + 1];
        unsigned v0 = *reinterpret_cast<const unsigned*>(&h[(size_t)e0 * D + lane * 2]);
        unsigned v1 = *reinterpret_cast<const unsigned*>(&h[(size_t)e1 * D + lane * 2]);
        a00 += bflo(v0); a01 += bfhi(v0);
        a10 += bflo(v1); a11 += bfhi(v1);
    }
    if (i < s1) {
        unsigned v0 = *reinterpret_cast<const unsigned*>(&h[(size_t)esrc[i] * D + lane * 2]);
        a00 += bflo(v0); a01 += bfhi(v0);
    }
    const float nrm = rsqrtf(fmaxf(degin[node], 1.0f));
    float2 o;
    o.x = (a00 + a10) * nrm + b[lane * 2];
    o.y = (a01 + a11) * nrm + b[lane * 2 + 1];
    *reinterpret_cast<float2*>(&h2[(size_t)node * D + lane * 2]) = o;
}

// ---------------- Kernel 4: column sums / sumsq of h2 ----------------
__global__ __launch_bounds__(256) void k_stats(const float* __restrict__ h2,
                                               float* __restrict__ stats) {
    __shared__ float sh1[256], sh2[256];
    const int t = threadIdx.x;
    const int c = t & 127;
    float s1 = 0.0f, s2 = 0.0f;
    const long total = (long)NN * D;
    const long stride = (long)gridDim.x * 256;
    for (long i = (long)blockIdx.x * 256 + t; i < total; i += stride) {
        float v = h2[i];
        s1 += v;
        s2 += v * v;
    }
    sh1[t] = s1; sh2[t] = s2;
    __syncthreads();
    if (t < 128) {
        atomicAdd(&stats[c],       sh1[t] + sh1[t + 128]);
        atomicAdd(&stats[128 + c], sh2[t] + sh2[t + 128]);
    }
}

// ---------------- Kernel 5: BN + ReLU + residual ----------------
__global__ void k_final(const float* __restrict__ h2, const float* __restrict__ x,
                        const float* __restrict__ gamma, const float* __restrict__ beta,
                        const float* __restrict__ stats, float* __restrict__ out) {
    long i = (long)blockIdx.x * blockDim.x + threadIdx.x;
    const long total = (long)NN * D;
    if (i >= total) return;
    int c = (int)(i & 127);
    const float inv_n = 1.0f / (float)NN;
    float mean = stats[c] * inv_n;
    float var  = stats[128 + c] * inv_n - mean * mean;
    float v = h2[i];
    v = (v - mean) * rsqrtf(var + BN_EPS) * gamma[c] + beta[c];
    v = fmaxf(v, 0.0f);
    out[i] = v + x[i];
}

extern "C" void kernel_launch(void* const* d_in, const int* in_sizes, int n_in,
                              void* d_out, int out_size, void* d_ws, size_t ws_size,
                              hipStream_t stream) {
    const float* x     = (const float*)d_in[0];
    const int*   src   = (const int*)d_in[1];
    const int*   dst   = (const int*)d_in[2];
    const float* W     = (const float*)d_in[3];
    const float* b     = (const float*)d_in[4];
    const float* gamma = (const float*)d_in[5];
    const float* beta  = (const float*)d_in[6];
    float* out = (float*)d_out;

    // Workspace layout
    float* ws     = (float*)d_ws;
    float* h2     = ws;                               // NN*D floats (fully overwritten)
    float* degout = ws + (size_t)NN * D;              // NN  -- zeroed
    float* degin  = degout + NN;                      // NN  -- zeroed
    int*   cursor = (int*)(degin + NN);               // NN  -- zeroed
    float* stats  = (float*)(cursor + NN);            // 256 -- zeroed
    int*   ptr    = (int*)(stats + 256);              // NN+1
    int*   esrc   = ptr + (NN + 1);                   // NE
    ushort* WT    = (ushort*)(esrc + NE);             // 128*128 bf16
    int*   partial= (int*)(WT + D * D);               // SB ints

    // h (bf16) lives in d_out (overwritten by k_final at the end)
    ushort* h = (ushort*)d_out;

    // zero degout, degin, cursor, stats (contiguous): ~1.2 MB
    const size_t zero_bytes = ((size_t)3 * NN + 256) * sizeof(float);
    hipMemsetAsync(degout, 0, zero_bytes, stream);

    k_wcast<<<64, 256, 0, stream>>>(W, WT);
    k_deg<<<(NE + 255) / 256, 256, 0, stream>>>(src, dst, degout, degin);
    k_gemm<<<(NN + 63) / 64, 256, 0, stream>>>(x, degout, WT, h);
    k_scan1<<<SB, 256, 0, stream>>>(degin, partial);
    k_scan2<<<1, 512, 0, stream>>>(partial, ptr);
    k_scan3<<<SB, 256, 0, stream>>>(degin, partial, ptr);
    k_fill<<<(NE + 255) / 256, 256, 0, stream>>>(src, dst, ptr, cursor, esrc);
    k_agg<<<(NN + 3) / 4, 256, 0, stream>>>(h, ptr, esrc, degin, b, h2);
    k_stats<<<1024, 256, 0, stream>>>(h2, stats);
    k_final<<<((long)NN * D + 255) / 256, 256, 0, stream>>>(h2, x, gamma, beta, stats, out);
}

// Round 5
// 428.028 us; speedup vs baseline: 2.5800x; 1.0799x over previous
//
#include <hip/hip_runtime.h>
#include <hip/hip_bf16.h>

#define NN 100000
#define NE 1600000
#define D  128
#define BN_EPS 1e-5f
#define SB 391   // scan blocks = ceil(NN/256)
#define NREP 8   // degree-counter replicas

typedef __attribute__((ext_vector_type(8))) short bf16x8;
typedef __attribute__((ext_vector_type(4))) float f32x4;

#define WLD 136   // padded row stride (ushorts) for W^T in LDS: 2-way banks only

static __device__ __forceinline__ ushort f2bf(float f) {
    __hip_bfloat16 b = __float2bfloat16(f);
    return *reinterpret_cast<ushort*>(&b);
}
static __device__ __forceinline__ float bflo(unsigned v) {
    return __uint_as_float((v & 0xffffu) << 16);
}
static __device__ __forceinline__ float bfhi(unsigned v) {
    return __uint_as_float(v & 0xffff0000u);
}

// ---------------- Kernel 0: W^T cast to bf16 ----------------
__global__ void k_wcast(const float* __restrict__ W, ushort* __restrict__ WT) {
    int i = blockIdx.x * 256 + threadIdx.x;   // 16384
    int n = i >> 7, k = i & 127;
    WT[i] = f2bf(W[k * D + n]);               // WT[n][k] = W[k][n]
}

// ---------------- Kernel 1: degree counts into 8 replicas (contention spread) ----------------
__global__ void k_deg(const int* __restrict__ src, const int* __restrict__ dst,
                      int* __restrict__ dgo_r, int* __restrict__ dgi_r) {
    int e = blockIdx.x * blockDim.x + threadIdx.x;
    const int rep = (blockIdx.x & (NREP - 1)) * NN;
    if (e < NE) {
        atomicAdd(&dgo_r[rep + src[e]], 1);
        atomicAdd(&dgi_r[rep + dst[e]], 1);
    }
}

// ---------------- Kernel 1b: merge replicas -> float degrees ----------------
__global__ void k_degmerge(const int* __restrict__ dgo_r, const int* __restrict__ dgi_r,
                           float* __restrict__ degout, float* __restrict__ degin) {
    int i = blockIdx.x * 256 + threadIdx.x;
    if (i >= NN) return;
    int so = 0, si = 0;
#pragma unroll
    for (int r = 0; r < NREP; ++r) {
        so += dgo_r[r * NN + i];
        si += dgi_r[r * NN + i];
    }
    degout[i] = (float)so;
    degin[i]  = (float)si;
}

// ---------------- Kernel 2: h(bf16) = (x * rsqrt(max(deg_out,1))) @ W via MFMA ----------------
__global__ __launch_bounds__(256) void k_gemm(const float* __restrict__ x,
                                              const float* __restrict__ degout,
                                              const ushort* __restrict__ WT,
                                              ushort* __restrict__ h) {
    __shared__ ushort Wl[D * WLD];   // 34.8 KB

    const int t = threadIdx.x;
    for (int s = t; s < 2048; s += 256) {
        int row = s >> 4, slot = s & 15;
        uint4 v = *reinterpret_cast<const uint4*>(WT + row * D + slot * 8);
        *reinterpret_cast<uint4*>(&Wl[row * WLD + slot * 8]) = v;
    }
    __syncthreads();

    const int wave = t >> 6;
    const int lane = t & 63;
    const int m16  = lane & 15;
    const int kq   = lane >> 4;
    const int row  = blockIdx.x * 64 + wave * 16 + m16;
    const int rc   = row < NN ? row : NN - 1;

    const float nrm = rsqrtf(fmaxf(degout[rc], 1.0f));

    bf16x8 afrag[4];
    const float* xr = x + (size_t)rc * D + kq * 8;
#pragma unroll
    for (int kt = 0; kt < 4; ++kt) {
        f32x4 lo = *reinterpret_cast<const f32x4*>(xr + kt * 32);
        f32x4 hi = *reinterpret_cast<const f32x4*>(xr + kt * 32 + 4);
        union { bf16x8 v; ushort u[8]; } af;
#pragma unroll
        for (int j = 0; j < 4; ++j) {
            af.u[j]     = f2bf(lo[j] * nrm);
            af.u[4 + j] = f2bf(hi[j] * nrm);
        }
        afrag[kt] = af.v;
    }

    f32x4 acc[8];
#pragma unroll
    for (int nt = 0; nt < 8; ++nt) acc[nt] = (f32x4)(0.0f);

#pragma unroll
    for (int kt = 0; kt < 4; ++kt) {
#pragma unroll
        for (int nt = 0; nt < 8; ++nt) {
            int n = nt * 16 + m16;
            const bf16x8 bfrag = *reinterpret_cast<const bf16x8*>(
                &Wl[n * WLD + kt * 32 + kq * 8]);
            acc[nt] = __builtin_amdgcn_mfma_f32_16x16x32_bf16(afrag[kt], bfrag, acc[nt], 0, 0, 0);
        }
    }

    const int orow = blockIdx.x * 64 + wave * 16 + kq * 4;
#pragma unroll
    for (int nt = 0; nt < 8; ++nt) {
#pragma unroll
        for (int r = 0; r < 4; ++r) {
            int rr = orow + r;
            if (rr < NN) h[(size_t)rr * D + nt * 16 + m16] = f2bf(acc[nt][r]);
        }
    }
}

// ---------------- Kernel 3a: multi-block exclusive scan of degin -> ptr ----------------
__global__ __launch_bounds__(256) void k_scan1(const float* __restrict__ degin,
                                               int* __restrict__ partial) {
    __shared__ int red[256];
    const int t = threadIdx.x;
    const int i = blockIdx.x * 256 + t;
    red[t] = (i < NN) ? (int)degin[i] : 0;
    __syncthreads();
    for (int off = 128; off > 0; off >>= 1) {
        if (t < off) red[t] += red[t + off];
        __syncthreads();
    }
    if (t == 0) partial[blockIdx.x] = red[0];
}

__global__ __launch_bounds__(512) void k_scan2(int* __restrict__ partial,
                                               int* __restrict__ ptr) {
    __shared__ int sh[512];
    const int t = threadIdx.x;
    sh[t] = (t < SB) ? partial[t] : 0;
    __syncthreads();
    for (int off = 1; off < 512; off <<= 1) {
        int u = (t >= off) ? sh[t - off] : 0;
        __syncthreads();
        sh[t] += u;
        __syncthreads();
    }
    if (t < SB) partial[t] = (t == 0) ? 0 : sh[t - 1];   // exclusive block offsets
    if (t == 511) ptr[NN] = sh[511];                      // total = NE
}

__global__ __launch_bounds__(256) void k_scan3(const float* __restrict__ degin,
                                               const int* __restrict__ partial,
                                               int* __restrict__ ptr) {
    __shared__ int sh[256];
    const int t = threadIdx.x;
    const int i = blockIdx.x * 256 + t;
    const int v = (i < NN) ? (int)degin[i] : 0;
    sh[t] = v;
    __syncthreads();
    for (int off = 1; off < 256; off <<= 1) {
        int u = (t >= off) ? sh[t - off] : 0;
        __syncthreads();
        sh[t] += u;
        __syncthreads();
    }
    if (i < NN) ptr[i] = partial[blockIdx.x] + sh[t] - v;  // exclusive prefix
}

// ---------------- Kernel 3b: fill CSR edge array (src ids grouped by dst) ----------------
__global__ void k_fill(const int* __restrict__ src, const int* __restrict__ dst,
                       const int* __restrict__ ptr, int* __restrict__ cursor,
                       int* __restrict__ esrc) {
    int e = blockIdx.x * blockDim.x + threadIdx.x;
    if (e < NE) {
        int d = dst[e];
        int p = atomicAdd(&cursor[d], 1);
        esrc[ptr[d] + p] = src[e];
    }
}

// ---------------- Kernel 3c: per-node gather-sum of bf16 h, fused *norm_dst + b ----------------
__global__ __launch_bounds__(256) void k_agg(const ushort* __restrict__ h,
                                             const int* __restrict__ ptr,
                                             const int* __restrict__ esrc,
                                             const float* __restrict__ degin,
                                             const float* __restrict__ b,
                                             float* __restrict__ h2) {
    const int node = blockIdx.x * 4 + (threadIdx.x >> 6);
    const int lane = threadIdx.x & 63;
    if (node >= NN) return;
    const int s0 = ptr[node];
    const int s1 = ptr[node + 1];
    float a00 = 0.f, a01 = 0.f, a10 = 0.f, a11 = 0.f;
    int i = s0;
    for (; i + 1 < s1; i += 2) {
        int e0 = esrc[i], e1 = esrc[i + 1];
        unsigned v0 = *reinterpret_cast<const unsigned*>(&h[(size_t)e0 * D + lane * 2]);
        unsigned v1 = *reinterpret_cast<const unsigned*>(&h[(size_t)e1 * D + lane * 2]);
        a00 += bflo(v0); a01 += bfhi(v0);
        a10 += bflo(v1); a11 += bfhi(v1);
    }
    if (i < s1) {
        unsigned v0 = *reinterpret_cast<const unsigned*>(&h[(size_t)esrc[i] * D + lane * 2]);
        a00 += bflo(v0); a01 += bfhi(v0);
    }
    const float nrm = rsqrtf(fmaxf(degin[node], 1.0f));
    float2 o;
    o.x = (a00 + a10) * nrm + b[lane * 2];
    o.y = (a01 + a11) * nrm + b[lane * 2 + 1];
    *reinterpret_cast<float2*>(&h2[(size_t)node * D + lane * 2]) = o;
}

// ---------------- Kernel 4: column sums / sumsq of h2 ----------------
__global__ __launch_bounds__(256) void k_stats(const float* __restrict__ h2,
                                               float* __restrict__ stats) {
    __shared__ float sh1[256], sh2[256];
    const int t = threadIdx.x;
    const int c = t & 127;
    float s1 = 0.0f, s2 = 0.0f;
    const long total = (long)NN * D;
    const long stride = (long)gridDim.x * 256;
    for (long i = (long)blockIdx.x * 256 + t; i < total; i += stride) {
        float v = h2[i];
        s1 += v;
        s2 += v * v;
    }
    sh1[t] = s1; sh2[t] = s2;
    __syncthreads();
    if (t < 128) {
        atomicAdd(&stats[c],       sh1[t] + sh1[t + 128]);
        atomicAdd(&stats[128 + c], sh2[t] + sh2[t + 128]);
    }
}

// ---------------- Kernel 5: BN + ReLU + residual ----------------
__global__ void k_final(const float* __restrict__ h2, const float* __restrict__ x,
                        const float* __restrict__ gamma, const float* __restrict__ beta,
                        const float* __restrict__ stats, float* __restrict__ out) {
    long i = (long)blockIdx.x * blockDim.x + threadIdx.x;
    const long total = (long)NN * D;
    if (i >= total) return;
    int c = (int)(i & 127);
    const float inv_n = 1.0f / (float)NN;
    float mean = stats[c] * inv_n;
    float var  = stats[128 + c] * inv_n - mean * mean;
    float v = h2[i];
    v = (v - mean) * rsqrtf(var + BN_EPS) * gamma[c] + beta[c];
    v = fmaxf(v, 0.0f);
    out[i] = v + x[i];
}

extern "C" void kernel_launch(void* const* d_in, const int* in_sizes, int n_in,
                              void* d_out, int out_size, void* d_ws, size_t ws_size,
                              hipStream_t stream) {
    const float* x     = (const float*)d_in[0];
    const int*   src   = (const int*)d_in[1];
    const int*   dst   = (const int*)d_in[2];
    const float* W     = (const float*)d_in[3];
    const float* b     = (const float*)d_in[4];
    const float* gamma = (const float*)d_in[5];
    const float* beta  = (const float*)d_in[6];
    float* out = (float*)d_out;

    // Workspace layout
    float* ws     = (float*)d_ws;
    float* h2     = ws;                               // NN*D floats (fully overwritten by k_agg)
    float* degout = ws + (size_t)NN * D;              // NN
    float* degin  = degout + NN;                      // NN
    int*   cursor = (int*)(degin + NN);               // NN  -- zeroed
    float* stats  = (float*)(cursor + NN);            // 256 -- zeroed
    int*   ptr    = (int*)(stats + 256);              // NN+1
    int*   esrc   = ptr + (NN + 1);                   // NE
    ushort* WT    = (ushort*)(esrc + NE);             // 128*128 bf16
    int*   partial= (int*)(WT + D * D);               // SB ints

    // degree replicas overlay the h2 region (h2 not written until k_agg)
    int* dgo_r = (int*)h2;                            // NREP*NN ints
    int* dgi_r = dgo_r + (size_t)NREP * NN;           // NREP*NN ints

    // h (bf16) lives in d_out (overwritten by k_final at the end)
    ushort* h = (ushort*)d_out;

    // zero replicas (6.4 MB) and cursor+stats
    hipMemsetAsync(dgo_r, 0, (size_t)2 * NREP * NN * sizeof(int), stream);
    hipMemsetAsync(cursor, 0, (size_t)(NN + 256) * sizeof(int), stream);

    k_wcast<<<64, 256, 0, stream>>>(W, WT);
    k_deg<<<(NE + 255) / 256, 256, 0, stream>>>(src, dst, dgo_r, dgi_r);
    k_degmerge<<<(NN + 255) / 256, 256, 0, stream>>>(dgo_r, dgi_r, degout, degin);
    k_gemm<<<(NN + 63) / 64, 256, 0, stream>>>(x, degout, WT, h);
    k_scan1<<<SB, 256, 0, stream>>>(degin, partial);
    k_scan2<<<1, 512, 0, stream>>>(partial, ptr);
    k_scan3<<<SB, 256, 0, stream>>>(degin, partial, ptr);
    k_fill<<<(NE + 255) / 256, 256, 0, stream>>>(src, dst, ptr, cursor, esrc);
    k_agg<<<(NN + 3) / 4, 256, 0, stream>>>(h, ptr, esrc, degin, b, h2);
    k_stats<<<1024, 256, 0, stream>>>(h2, stats);
    k_final<<<((long)NN * D + 255) / 256, 256, 0, stream>>>(h2, x, gamma, beta, stats, out);
}

// Round 6
// 393.418 us; speedup vs baseline: 2.8069x; 1.0880x over previous
//
#include <hip/hip_runtime.h>
#include <hip/hip_bf16.h>

#define NN 100000
#define NE 1600000
#define D  128
#define BN_EPS 1e-5f
#define SB 391   // scan blocks = ceil(NN/256)
#define NREP 8   // one degree-counter replica per XCD

// s_getreg imm: bits[5:0]=id(HW_REG_XCC_ID=20), [10:6]=offset(0), [15:11]=size-1(3 -> 4 bits)
#define XCC_GETREG_IMM 6164

typedef __attribute__((ext_vector_type(8))) short bf16x8;
typedef __attribute__((ext_vector_type(4))) float f32x4;

#define WLD 136   // padded row stride (ushorts) for W^T in LDS: 2-way banks only

static __device__ __forceinline__ ushort f2bf(float f) {
    __hip_bfloat16 b = __float2bfloat16(f);
    return *reinterpret_cast<ushort*>(&b);
}
static __device__ __forceinline__ float bflo(unsigned v) {
    return __uint_as_float((v & 0xffffu) << 16);
}
static __device__ __forceinline__ float bfhi(unsigned v) {
    return __uint_as_float(v & 0xffff0000u);
}

// ---------------- Kernel 0: W^T cast to bf16 ----------------
__global__ void k_wcast(const float* __restrict__ W, ushort* __restrict__ WT) {
    int i = blockIdx.x * 256 + threadIdx.x;   // 16384
    int n = i >> 7, k = i & 127;
    WT[i] = f2bf(W[k * D + n]);               // WT[n][k] = W[k][n]
}

// ---------------- Kernel 1: degree counts, XCD-local replicas + rank capture ----------------
// Replica indexed by REAL XCC id -> each replica word touched by one XCD only,
// so workgroup-scope atomics (executed in local L2, no fabric write-through) are safe.
__global__ void k_deg(const int* __restrict__ src, const int* __restrict__ dst,
                      int* __restrict__ dgo_r, int* __restrict__ dgi_r,
                      int* __restrict__ rankrep) {
    int e = blockIdx.x * blockDim.x + threadIdx.x;
    if (e >= NE) return;
    const int xcd = __builtin_amdgcn_s_getreg(XCC_GETREG_IMM) & (NREP - 1);
    const int rep = xcd * NN;
    __hip_atomic_fetch_add(&dgo_r[rep + src[e]], 1, __ATOMIC_RELAXED,
                           __HIP_MEMORY_SCOPE_WORKGROUP);
    int rk = __hip_atomic_fetch_add(&dgi_r[rep + dst[e]], 1, __ATOMIC_RELAXED,
                                    __HIP_MEMORY_SCOPE_WORKGROUP);
    rankrep[e] = (xcd << 24) | rk;
}

// ---------------- Kernel 1b: merge replicas -> degrees + per-replica bases ----------------
__global__ void k_degmerge(const int* __restrict__ dgo_r, const int* __restrict__ dgi_r,
                           float* __restrict__ degout, float* __restrict__ degin,
                           int* __restrict__ base8) {
    int i = blockIdx.x * 256 + threadIdx.x;
    if (i >= NN) return;
    int so = 0;
#pragma unroll
    for (int r = 0; r < NREP; ++r) so += dgo_r[r * NN + i];
    degout[i] = (float)so;
    int run = 0;
#pragma unroll
    for (int r = 0; r < NREP; ++r) {
        base8[i * NREP + r] = run;
        run += dgi_r[r * NN + i];
    }
    degin[i] = (float)run;
}

// ---------------- Kernel 2: h(bf16) = (x * rsqrt(max(deg_out,1))) @ W via MFMA ----------------
__global__ __launch_bounds__(256) void k_gemm(const float* __restrict__ x,
                                              const float* __restrict__ degout,
                                              const ushort* __restrict__ WT,
                                              ushort* __restrict__ h) {
    __shared__ ushort Wl[D * WLD];   // 34.8 KB

    const int t = threadIdx.x;
    for (int s = t; s < 2048; s += 256) {
        int row = s >> 4, slot = s & 15;
        uint4 v = *reinterpret_cast<const uint4*>(WT + row * D + slot * 8);
        *reinterpret_cast<uint4*>(&Wl[row * WLD + slot * 8]) = v;
    }
    __syncthreads();

    const int wave = t >> 6;
    const int lane = t & 63;
    const int m16  = lane & 15;
    const int kq   = lane >> 4;
    const int row  = blockIdx.x * 64 + wave * 16 + m16;
    const int rc   = row < NN ? row : NN - 1;

    const float nrm = rsqrtf(fmaxf(degout[rc], 1.0f));

    bf16x8 afrag[4];
    const float* xr = x + (size_t)rc * D + kq * 8;
#pragma unroll
    for (int kt = 0; kt < 4; ++kt) {
        f32x4 lo = *reinterpret_cast<const f32x4*>(xr + kt * 32);
        f32x4 hi = *reinterpret_cast<const f32x4*>(xr + kt * 32 + 4);
        union { bf16x8 v; ushort u[8]; } af;
#pragma unroll
        for (int j = 0; j < 4; ++j) {
            af.u[j]     = f2bf(lo[j] * nrm);
            af.u[4 + j] = f2bf(hi[j] * nrm);
        }
        afrag[kt] = af.v;
    }

    f32x4 acc[8];
#pragma unroll
    for (int nt = 0; nt < 8; ++nt) acc[nt] = (f32x4)(0.0f);

#pragma unroll
    for (int kt = 0; kt < 4; ++kt) {
#pragma unroll
        for (int nt = 0; nt < 8; ++nt) {
            int n = nt * 16 + m16;
            const bf16x8 bfrag = *reinterpret_cast<const bf16x8*>(
                &Wl[n * WLD + kt * 32 + kq * 8]);
            acc[nt] = __builtin_amdgcn_mfma_f32_16x16x32_bf16(afrag[kt], bfrag, acc[nt], 0, 0, 0);
        }
    }

    const int orow = blockIdx.x * 64 + wave * 16 + kq * 4;
#pragma unroll
    for (int nt = 0; nt < 8; ++nt) {
#pragma unroll
        for (int r = 0; r < 4; ++r) {
            int rr = orow + r;
            if (rr < NN) h[(size_t)rr * D + nt * 16 + m16] = f2bf(acc[nt][r]);
        }
    }
}

// ---------------- Kernel 3a: multi-block exclusive scan of degin -> ptr ----------------
__global__ __launch_bounds__(256) void k_scan1(const float* __restrict__ degin,
                                               int* __restrict__ partial) {
    __shared__ int red[256];
    const int t = threadIdx.x;
    const int i = blockIdx.x * 256 + t;
    red[t] = (i < NN) ? (int)degin[i] : 0;
    __syncthreads();
    for (int off = 128; off > 0; off >>= 1) {
        if (t < off) red[t] += red[t + off];
        __syncthreads();
    }
    if (t == 0) partial[blockIdx.x] = red[0];
}

__global__ __launch_bounds__(512) void k_scan2(int* __restrict__ partial,
                                               int* __restrict__ ptr) {
    __shared__ int sh[512];
    const int t = threadIdx.x;
    sh[t] = (t < SB) ? partial[t] : 0;
    __syncthreads();
    for (int off = 1; off < 512; off <<= 1) {
        int u = (t >= off) ? sh[t - off] : 0;
        __syncthreads();
        sh[t] += u;
        __syncthreads();
    }
    if (t < SB) partial[t] = (t == 0) ? 0 : sh[t - 1];   // exclusive block offsets
    if (t == 511) ptr[NN] = sh[511];                      // total = NE
}

__global__ __launch_bounds__(256) void k_scan3(const float* __restrict__ degin,
                                               const int* __restrict__ partial,
                                               int* __restrict__ ptr) {
    __shared__ int sh[256];
    const int t = threadIdx.x;
    const int i = blockIdx.x * 256 + t;
    const int v = (i < NN) ? (int)degin[i] : 0;
    sh[t] = v;
    __syncthreads();
    for (int off = 1; off < 256; off <<= 1) {
        int u = (t >= off) ? sh[t - off] : 0;
        __syncthreads();
        sh[t] += u;
        __syncthreads();
    }
    if (i < NN) ptr[i] = partial[blockIdx.x] + sh[t] - v;  // exclusive prefix
}

// ---------------- Kernel 3b: fill CSR edge array -- NO atomics (rank trick) ----------------
__global__ void k_fill2(const int* __restrict__ src, const int* __restrict__ dst,
                        const int* __restrict__ ptr, const int* __restrict__ base8,
                        const int* __restrict__ rankrep, int* __restrict__ esrc) {
    int e = blockIdx.x * blockDim.x + threadIdx.x;
    if (e >= NE) return;
    int d  = dst[e];
    int rr = rankrep[e];
    int pos = ptr[d] + base8[d * NREP + (rr >> 24)] + (rr & 0xFFFFFF);
    esrc[pos] = src[e];
}

// ---------------- Kernel 3c: per-node gather-sum of bf16 h, fused *norm_dst + b ----------------
__global__ __launch_bounds__(256) void k_agg(const ushort* __restrict__ h,
                                             const int* __restrict__ ptr,
                                             const int* __restrict__ esrc,
                                             const float* __restrict__ degin,
                                             const float* __restrict__ b,
                                             float* __restrict__ h2) {
    const int node = blockIdx.x * 4 + (threadIdx.x >> 6);
    const int lane = threadIdx.x & 63;
    if (node >= NN) return;
    const int s0 = ptr[node];
    const int s1 = ptr[node + 1];
    float a00 = 0.f, a01 = 0.f, a10 = 0.f, a11 = 0.f;
    int i = s0;
    for (; i + 1 < s1; i += 2) {
        int e0 = esrc[i], e1 = esrc[i + 1];
        unsigned v0 = *reinterpret_cast<const unsigned*>(&h[(size_t)e0 * D + lane * 2]);
        unsigned v1 = *reinterpret_cast<const unsigned*>(&h[(size_t)e1 * D + lane * 2]);
        a00 += bflo(v0); a01 += bfhi(v0);
        a10 += bflo(v1); a11 += bfhi(v1);
    }
    if (i < s1) {
        unsigned v0 = *reinterpret_cast<const unsigned*>(&h[(size_t)esrc[i] * D + lane * 2]);
        a00 += bflo(v0); a01 += bfhi(v0);
    }
    const float nrm = rsqrtf(fmaxf(degin[node], 1.0f));
    float2 o;
    o.x = (a00 + a10) * nrm + b[lane * 2];
    o.y = (a01 + a11) * nrm + b[lane * 2 + 1];
    *reinterpret_cast<float2*>(&h2[(size_t)node * D + lane * 2]) = o;
}

// ---------------- Kernel 4: column sums / sumsq of h2 ----------------
__global__ __launch_bounds__(256) void k_stats(const float* __restrict__ h2,
                                               float* __restrict__ stats) {
    __shared__ float sh1[256], sh2[256];
    const int t = threadIdx.x;
    const int c = t & 127;
    float s1 = 0.0f, s2 = 0.0f;
    const long total = (long)NN * D;
    const long stride = (long)gridDim.x * 256;
    for (long i = (long)blockIdx.x * 256 + t; i < total; i += stride) {
        float v = h2[i];
        s1 += v;
        s2 += v * v;
    }
    sh1[t] = s1; sh2[t] = s2;
    __syncthreads();
    if (t < 128) {
        atomicAdd(&stats[c],       sh1[t] + sh1[t + 128]);
        atomicAdd(&stats[128 + c], sh2[t] + sh2[t + 128]);
    }
}

// ---------------- Kernel 5: BN + ReLU + residual ----------------
__global__ void k_final(const float* __restrict__ h2, const float* __restrict__ x,
                        const float* __restrict__ gamma, const float* __restrict__ beta,
                        const float* __restrict__ stats, float* __restrict__ out) {
    long i = (long)blockIdx.x * blockDim.x + threadIdx.x;
    const long total = (long)NN * D;
    if (i >= total) return;
    int c = (int)(i & 127);
    const float inv_n = 1.0f / (float)NN;
    float mean = stats[c] * inv_n;
    float var  = stats[128 + c] * inv_n - mean * mean;
    float v = h2[i];
    v = (v - mean) * rsqrtf(var + BN_EPS) * gamma[c] + beta[c];
    v = fmaxf(v, 0.0f);
    out[i] = v + x[i];
}

extern "C" void kernel_launch(void* const* d_in, const int* in_sizes, int n_in,
                              void* d_out, int out_size, void* d_ws, size_t ws_size,
                              hipStream_t stream) {
    const float* x     = (const float*)d_in[0];
    const int*   src   = (const int*)d_in[1];
    const int*   dst   = (const int*)d_in[2];
    const float* W     = (const float*)d_in[3];
    const float* b     = (const float*)d_in[4];
    const float* gamma = (const float*)d_in[5];
    const float* beta  = (const float*)d_in[6];
    float* out = (float*)d_out;

    // Workspace layout
    float* ws     = (float*)d_ws;
    float* h2     = ws;                               // NN*D floats (fully overwritten by k_agg)
    float* degout = ws + (size_t)NN * D;              // NN
    float* degin  = degout + NN;                      // NN
    float* stats  = degin + NN;                       // 256 -- zeroed
    int*   ptr    = (int*)(stats + 256);              // NN+1
    int*   esrc   = ptr + (NN + 1);                   // NE
    ushort* WT    = (ushort*)(esrc + NE);             // 128*128 bf16
    int*   partial= (int*)(WT + D * D);               // SB ints

    // Overlays in the h2 region (all dead before k_agg writes h2):
    int* dgo_r = (int*)h2;                            // NREP*NN ints
    int* dgi_r = dgo_r + (size_t)NREP * NN;           // NREP*NN ints
    int* base8 = dgi_r + (size_t)NREP * NN;           // NREP*NN ints

    // h (bf16) in d_out lower half; rankrep in d_out upper half
    // (both dead before k_final overwrites d_out)
    ushort* h = (ushort*)d_out;
    int* rankrep = (int*)((char*)d_out + (size_t)NN * D * 2);   // NE ints (6.4MB < 25.6MB)

    // zero replicas (6.4 MB) and stats
    hipMemsetAsync(dgo_r, 0, (size_t)2 * NREP * NN * sizeof(int), stream);
    hipMemsetAsync(stats, 0, 256 * sizeof(float), stream);

    k_wcast<<<64, 256, 0, stream>>>(W, WT);
    k_deg<<<(NE + 255) / 256, 256, 0, stream>>>(src, dst, dgo_r, dgi_r, rankrep);
    k_degmerge<<<(NN + 255) / 256, 256, 0, stream>>>(dgo_r, dgi_r, degout, degin, base8);
    k_gemm<<<(NN + 63) / 64, 256, 0, stream>>>(x, degout, WT, h);
    k_scan1<<<SB, 256, 0, stream>>>(degin, partial);
    k_scan2<<<1, 512, 0, stream>>>(partial, ptr);
    k_scan3<<<SB, 256, 0, stream>>>(degin, partial, ptr);
    k_fill2<<<(NE + 255) / 256, 256, 0, stream>>>(src, dst, ptr, base8, rankrep, esrc);
    k_agg<<<(NN + 3) / 4, 256, 0, stream>>>(h, ptr, esrc, degin, b, h2);
    k_stats<<<1024, 256, 0, stream>>>(h2, stats);
    k_final<<<((long)NN * D + 255) / 256, 256, 0, stream>>>(h2, x, gamma, beta, stats, out);
}

// Round 7
// 317.215 us; speedup vs baseline: 3.4812x; 1.2402x over previous
//
#include <hip/hip_runtime.h>
#include <hip/hip_bf16.h>

#define NN 100000
#define NE 1600000
#define D  128
#define BN_EPS 1e-5f

// counting-sort geometry (dst path)
#define CB  782                 // coarse bins = ceil(NN/128), bin = 128 nodes
#define NC  256                 // chunks
#define EPC (NE / NC)           // 6250 edges per chunk
// slice-histogram geometry (src path)
#define NSLICE  13
#define SLICESZ 7700            // 13*7700 = 100100 >= NN
#define SCH     32
#define EPH (NE / SCH)          // 50000

typedef __attribute__((ext_vector_type(8))) short bf16x8;
typedef __attribute__((ext_vector_type(4))) float f32x4;

#define WLD 136   // padded row stride (ushorts) for W^T in LDS: 2-way banks only

static __device__ __forceinline__ ushort f2bf(float f) {
    __hip_bfloat16 b = __float2bfloat16(f);
    return *reinterpret_cast<ushort*>(&b);
}
static __device__ __forceinline__ float bflo(unsigned v) {
    return __uint_as_float((v & 0xffffu) << 16);
}
static __device__ __forceinline__ float bfhi(unsigned v) {
    return __uint_as_float(v & 0xffff0000u);
}

// ---------------- Kernel 0: W^T cast to bf16 ----------------
__global__ void k_wcast(const float* __restrict__ W, ushort* __restrict__ WT) {
    int i = blockIdx.x * 256 + threadIdx.x;   // 16384
    int n = i >> 7, k = i & 127;
    WT[i] = f2bf(W[k * D + n]);               // WT[n][k] = W[k][n]
}

// ======== dst counting-sort pipeline (no global atomics) ========

// Phase A: per-chunk coarse histogram of dst (LDS atomics only)
__global__ __launch_bounds__(256) void k_ccount(const int* __restrict__ dst,
                                                int* __restrict__ P /*[CB][NC]*/) {
    __shared__ int hist[CB];
    const int c = blockIdx.x;
    const int t = threadIdx.x;
    for (int i = t; i < CB; i += 256) hist[i] = 0;
    __syncthreads();
    const int base = c * EPC;
    for (int i = t; i < EPC; i += 256)
        atomicAdd(&hist[dst[base + i] >> 7], 1);
    __syncthreads();
    for (int i = t; i < CB; i += 256) P[i * NC + c] = hist[i];
}

// Phase B1: per-bin exclusive scan over the NC chunks; emit bintotal
__global__ __launch_bounds__(256) void k_cscanA(int* __restrict__ P,
                                                int* __restrict__ bintotal) {
    __shared__ int sh[NC];
    const int b = blockIdx.x;
    const int t = threadIdx.x;
    const int v = P[b * NC + t];
    sh[t] = v;
    __syncthreads();
    for (int off = 1; off < NC; off <<= 1) {
        int u = (t >= off) ? sh[t - off] : 0;
        __syncthreads();
        sh[t] += u;
        __syncthreads();
    }
    P[b * NC + t] = sh[t] - v;            // exclusive prefix within bin
    if (t == NC - 1) bintotal[b] = sh[t];
}

// Phase B2: exclusive scan of bintotal -> binbase[CB+1]
__global__ __launch_bounds__(1024) void k_cscanB(const int* __restrict__ bintotal,
                                                 int* __restrict__ binbase) {
    __shared__ int sh[1024];
    const int t = threadIdx.x;
    const int v = (t < CB) ? bintotal[t] : 0;
    sh[t] = v;
    __syncthreads();
    for (int off = 1; off < 1024; off <<= 1) {
        int u = (t >= off) ? sh[t - off] : 0;
        __syncthreads();
        sh[t] += u;
        __syncthreads();
    }
    if (t < CB) binbase[t] = sh[t] - v;
    if (t == CB - 1) binbase[CB] = sh[t];    // = NE
}

// Phase C: scatter (dst,src) into coarse-bin-grouped order (LDS cursors)
__global__ __launch_bounds__(256) void k_cscatter(const int* __restrict__ dst,
                                                  const int* __restrict__ src,
                                                  const int* __restrict__ P,
                                                  const int* __restrict__ binbase,
                                                  int* __restrict__ skey,
                                                  int* __restrict__ sval) {
    __shared__ int cur[CB];
    const int c = blockIdx.x;
    const int t = threadIdx.x;
    for (int i = t; i < CB; i += 256) cur[i] = binbase[i] + P[i * NC + c];
    __syncthreads();
    const int base = c * EPC;
    for (int i = t; i < EPC; i += 256) {
        int d = dst[base + i];
        int pos = atomicAdd(&cur[d >> 7], 1);   // LDS atomic
        skey[pos] = d;
        sval[pos] = src[base + i];
    }
}

// Phase D: per-coarse-bin fine CSR: 128-bin LDS hist + scan + scatter.
// Emits ptr, degin (float), esrc.
__global__ __launch_bounds__(256) void k_fine(const int* __restrict__ skey,
                                              const int* __restrict__ sval,
                                              const int* __restrict__ binbase,
                                              int* __restrict__ ptr,
                                              float* __restrict__ degin,
                                              int* __restrict__ esrc) {
    __shared__ int fh[128], fp[128], fcur[128];
    const int b = blockIdx.x;
    const int t = threadIdx.x;
    const int lo = binbase[b], hi = binbase[b + 1];
    if (t < 128) fh[t] = 0;
    __syncthreads();
    for (int i = lo + t; i < hi; i += 256)
        atomicAdd(&fh[skey[i] & 127], 1);
    __syncthreads();
    if (t < 128) fp[t] = fh[t];
    __syncthreads();
    for (int off = 1; off < 128; off <<= 1) {
        int u = (t < 128 && t >= off) ? fp[t - off] : 0;
        __syncthreads();
        if (t < 128) fp[t] += u;
        __syncthreads();
    }
    if (t < 128) {
        const int node = b * 128 + t;
        const int ex = fp[t] - fh[t];       // exclusive prefix within bin
        fcur[t] = ex;
        if (node < NN) {
            ptr[node] = lo + ex;
            degin[node] = (float)fh[t];
        } else if (node == NN) {
            ptr[NN] = lo + ex;              // = NE (trailing bins empty)
        }
    }
    __syncthreads();
    for (int i = lo + t; i < hi; i += 256) {
        int d = skey[i];
        int pos = atomicAdd(&fcur[d & 127], 1);   // LDS atomic
        esrc[lo + pos] = sval[i];
    }
}

// ======== src slice-histogram (deg_out, no global atomics) ========

__global__ __launch_bounds__(256) void k_shist(const int* __restrict__ src,
                                               int* __restrict__ SP /*[NSLICE][SCH][SLICESZ]*/) {
    __shared__ int hist[SLICESZ];
    const int s = blockIdx.x / SCH;
    const int c = blockIdx.x % SCH;
    const int t = threadIdx.x;
    const int lo = s * SLICESZ;
    for (int i = t; i < SLICESZ; i += 256) hist[i] = 0;
    __syncthreads();
    const int base = c * EPH;
    for (int i = t; i < EPH; i += 256) {
        int k = src[base + i] - lo;
        if ((unsigned)k < (unsigned)SLICESZ) atomicAdd(&hist[k], 1);
    }
    __syncthreads();
    int* out = SP + ((size_t)s * SCH + c) * SLICESZ;
    for (int i = t; i < SLICESZ; i += 256) out[i] = hist[i];
}

__global__ void k_smerge(const int* __restrict__ SP, float* __restrict__ degout) {
    int n = blockIdx.x * 256 + threadIdx.x;
    if (n >= NN) return;
    const int s = n / SLICESZ, k = n % SLICESZ;
    const int* col = SP + ((size_t)s * SCH) * SLICESZ + k;
    int sum = 0;
#pragma unroll
    for (int c = 0; c < SCH; ++c) sum += col[(size_t)c * SLICESZ];
    degout[n] = (float)sum;
}

// ---------------- Kernel 2: h(bf16) = (x * rsqrt(max(deg_out,1))) @ W via MFMA ----------------
__global__ __launch_bounds__(256) void k_gemm(const float* __restrict__ x,
                                              const float* __restrict__ degout,
                                              const ushort* __restrict__ WT,
                                              ushort* __restrict__ h) {
    __shared__ ushort Wl[D * WLD];   // 34.8 KB

    const int t = threadIdx.x;
    for (int s = t; s < 2048; s += 256) {
        int row = s >> 4, slot = s & 15;
        uint4 v = *reinterpret_cast<const uint4*>(WT + row * D + slot * 8);
        *reinterpret_cast<uint4*>(&Wl[row * WLD + slot * 8]) = v;
    }
    __syncthreads();

    const int wave = t >> 6;
    const int lane = t & 63;
    const int m16  = lane & 15;
    const int kq   = lane >> 4;
    const int row  = blockIdx.x * 64 + wave * 16 + m16;
    const int rc   = row < NN ? row : NN - 1;

    const float nrm = rsqrtf(fmaxf(degout[rc], 1.0f));

    bf16x8 afrag[4];
    const float* xr = x + (size_t)rc * D + kq * 8;
#pragma unroll
    for (int kt = 0; kt < 4; ++kt) {
        f32x4 lo = *reinterpret_cast<const f32x4*>(xr + kt * 32);
        f32x4 hi = *reinterpret_cast<const f32x4*>(xr + kt * 32 + 4);
        union { bf16x8 v; ushort u[8]; } af;
#pragma unroll
        for (int j = 0; j < 4; ++j) {
            af.u[j]     = f2bf(lo[j] * nrm);
            af.u[4 + j] = f2bf(hi[j] * nrm);
        }
        afrag[kt] = af.v;
    }

    f32x4 acc[8];
#pragma unroll
    for (int nt = 0; nt < 8; ++nt) acc[nt] = (f32x4)(0.0f);

#pragma unroll
    for (int kt = 0; kt < 4; ++kt) {
#pragma unroll
        for (int nt = 0; nt < 8; ++nt) {
            int n = nt * 16 + m16;
            const bf16x8 bfrag = *reinterpret_cast<const bf16x8*>(
                &Wl[n * WLD + kt * 32 + kq * 8]);
            acc[nt] = __builtin_amdgcn_mfma_f32_16x16x32_bf16(afrag[kt], bfrag, acc[nt], 0, 0, 0);
        }
    }

    const int orow = blockIdx.x * 64 + wave * 16 + kq * 4;
#pragma unroll
    for (int nt = 0; nt < 8; ++nt) {
#pragma unroll
        for (int r = 0; r < 4; ++r) {
            int rr = orow + r;
            if (rr < NN) h[(size_t)rr * D + nt * 16 + m16] = f2bf(acc[nt][r]);
        }
    }
}

// ---------------- Kernel 3c: per-node gather-sum of bf16 h, fused *norm_dst + b ----------------
__global__ __launch_bounds__(256) void k_agg(const ushort* __restrict__ h,
                                             const int* __restrict__ ptr,
                                             const int* __restrict__ esrc,
                                             const float* __restrict__ degin,
                                             const float* __restrict__ b,
                                             float* __restrict__ h2) {
    const int node = blockIdx.x * 4 + (threadIdx.x >> 6);
    const int lane = threadIdx.x & 63;
    if (node >= NN) return;
    const int s0 = ptr[node];
    const int s1 = ptr[node + 1];
    float a00 = 0.f, a01 = 0.f, a10 = 0.f, a11 = 0.f;
    int i = s0;
    for (; i + 1 < s1; i += 2) {
        int e0 = esrc[i], e1 = esrc[i + 1];
        unsigned v0 = *reinterpret_cast<const unsigned*>(&h[(size_t)e0 * D + lane * 2]);
        unsigned v1 = *reinterpret_cast<const unsigned*>(&h[(size_t)e1 * D + lane * 2]);
        a00 += bflo(v0); a01 += bfhi(v0);
        a10 += bflo(v1); a11 += bfhi(v1);
    }
    if (i < s1) {
        unsigned v0 = *reinterpret_cast<const unsigned*>(&h[(size_t)esrc[i] * D + lane * 2]);
        a00 += bflo(v0); a01 += bfhi(v0);
    }
    const float nrm = rsqrtf(fmaxf(degin[node], 1.0f));
    float2 o;
    o.x = (a00 + a10) * nrm + b[lane * 2];
    o.y = (a01 + a11) * nrm + b[lane * 2 + 1];
    *reinterpret_cast<float2*>(&h2[(size_t)node * D + lane * 2]) = o;
}

// ---------------- Kernel 4: column sums / sumsq of h2 ----------------
__global__ __launch_bounds__(256) void k_stats(const float* __restrict__ h2,
                                               float* __restrict__ stats) {
    __shared__ float sh1[256], sh2[256];
    const int t = threadIdx.x;
    const int c = t & 127;
    float s1 = 0.0f, s2 = 0.0f;
    const long total = (long)NN * D;
    const long stride = (long)gridDim.x * 256;
    for (long i = (long)blockIdx.x * 256 + t; i < total; i += stride) {
        float v = h2[i];
        s1 += v;
        s2 += v * v;
    }
    sh1[t] = s1; sh2[t] = s2;
    __syncthreads();
    if (t < 128) {
        atomicAdd(&stats[c],       sh1[t] + sh1[t + 128]);
        atomicAdd(&stats[128 + c], sh2[t] + sh2[t + 128]);
    }
}

// ---------------- Kernel 5: BN + ReLU + residual ----------------
__global__ void k_final(const float* __restrict__ h2, const float* __restrict__ x,
                        const float* __restrict__ gamma, const float* __restrict__ beta,
                        const float* __restrict__ stats, float* __restrict__ out) {
    long i = (long)blockIdx.x * blockDim.x + threadIdx.x;
    const long total = (long)NN * D;
    if (i >= total) return;
    int c = (int)(i & 127);
    const float inv_n = 1.0f / (float)NN;
    float mean = stats[c] * inv_n;
    float var  = stats[128 + c] * inv_n - mean * mean;
    float v = h2[i];
    v = (v - mean) * rsqrtf(var + BN_EPS) * gamma[c] + beta[c];
    v = fmaxf(v, 0.0f);
    out[i] = v + x[i];
}

extern "C" void kernel_launch(void* const* d_in, const int* in_sizes, int n_in,
                              void* d_out, int out_size, void* d_ws, size_t ws_size,
                              hipStream_t stream) {
    const float* x     = (const float*)d_in[0];
    const int*   src   = (const int*)d_in[1];
    const int*   dst   = (const int*)d_in[2];
    const float* W     = (const float*)d_in[3];
    const float* b     = (const float*)d_in[4];
    const float* gamma = (const float*)d_in[5];
    const float* beta  = (const float*)d_in[6];
    float* out = (float*)d_out;

    // Workspace layout
    float* ws     = (float*)d_ws;
    float* h2     = ws;                               // NN*D floats (written by k_agg)
    float* degout = ws + (size_t)NN * D;              // NN
    float* degin  = degout + NN;                      // NN
    float* stats  = degin + NN;                       // 256 -- zeroed
    int*   ptr    = (int*)(stats + 256);              // NN+1
    int*   esrc   = ptr + (NN + 1);                   // NE
    ushort* WT    = (ushort*)(esrc + NE);             // 128*128 bf16

    // Overlays in the h2 region (all dead before k_agg writes h2): ~26.5 MB < 51.2 MB
    int* skey     = (int*)h2;                         // NE
    int* sval     = skey + NE;                        // NE
    int* SP       = sval + NE;                        // NSLICE*SCH*SLICESZ
    int* P        = SP + (size_t)NSLICE * SCH * SLICESZ;  // CB*NC
    int* bintotal = P + (size_t)CB * NC;              // CB
    int* binbase  = bintotal + CB;                    // CB+1

    // h (bf16) lives in d_out (overwritten by k_final at the end)
    ushort* h = (ushort*)d_out;

    hipMemsetAsync(stats, 0, 256 * sizeof(float), stream);

    k_wcast<<<64, 256, 0, stream>>>(W, WT);
    // dst counting sort -> CSR (esrc, ptr, degin)
    k_ccount<<<NC, 256, 0, stream>>>(dst, P);
    k_cscanA<<<CB, 256, 0, stream>>>(P, bintotal);
    k_cscanB<<<1, 1024, 0, stream>>>(bintotal, binbase);
    k_cscatter<<<NC, 256, 0, stream>>>(dst, src, P, binbase, skey, sval);
    // src slice histogram -> degout
    k_shist<<<NSLICE * SCH, 256, 0, stream>>>(src, SP);
    k_smerge<<<(NN + 255) / 256, 256, 0, stream>>>(SP, degout);
    k_gemm<<<(NN + 63) / 64, 256, 0, stream>>>(x, degout, WT, h);
    k_fine<<<CB, 256, 0, stream>>>(skey, sval, binbase, ptr, degin, esrc);
    k_agg<<<(NN + 3) / 4, 256, 0, stream>>>(h, ptr, esrc, degin, b, h2);
    k_stats<<<1024, 256, 0, stream>>>(h2, stats);
    k_final<<<((long)NN * D + 255) / 256, 256, 0, stream>>>(h2, x, gamma, beta, stats, out);
}

// Round 8
// 298.278 us; speedup vs baseline: 3.7022x; 1.0635x over previous
//
#include <hip/hip_runtime.h>
#include <hip/hip_bf16.h>

#define NN 100000
#define NE 1600000
#define D  128
#define BN_EPS 1e-5f

// counting-sort geometry (dst path)
#define CB  782                 // coarse bins = ceil(NN/128), bin = 128 nodes
#define NC  256                 // chunks
#define EPC (NE / NC)           // 6250 edges per chunk
// slice-histogram geometry (src path)
#define NSLICE  13
#define SLICESZ 7700            // 13*7700 = 100100 >= NN
#define SCH     32
#define EPH (NE / SCH)          // 50000

typedef __attribute__((ext_vector_type(8))) short bf16x8;
typedef __attribute__((ext_vector_type(4))) float f32x4;

#define WLD 136   // padded row stride (ushorts) for W^T in LDS: 2-way banks only

static __device__ __forceinline__ ushort f2bf(float f) {
    __hip_bfloat16 b = __float2bfloat16(f);
    return *reinterpret_cast<ushort*>(&b);
}
static __device__ __forceinline__ float bflo(unsigned v) {
    return __uint_as_float((v & 0xffffu) << 16);
}
static __device__ __forceinline__ float bfhi(unsigned v) {
    return __uint_as_float(v & 0xffff0000u);
}

// ---------------- Kernel 0: W^T cast to bf16 ----------------
__global__ void k_wcast(const float* __restrict__ W, ushort* __restrict__ WT) {
    int i = blockIdx.x * 256 + threadIdx.x;   // 16384
    int n = i >> 7, k = i & 127;
    WT[i] = f2bf(W[k * D + n]);               // WT[n][k] = W[k][n]
}

// ======== dst counting-sort pipeline (no global atomics) ========

__global__ __launch_bounds__(256) void k_ccount(const int* __restrict__ dst,
                                                int* __restrict__ P /*[CB][NC]*/) {
    __shared__ int hist[CB];
    const int c = blockIdx.x;
    const int t = threadIdx.x;
    for (int i = t; i < CB; i += 256) hist[i] = 0;
    __syncthreads();
    const int base = c * EPC;
    for (int i = t; i < EPC; i += 256)
        atomicAdd(&hist[dst[base + i] >> 7], 1);
    __syncthreads();
    for (int i = t; i < CB; i += 256) P[i * NC + c] = hist[i];
}

__global__ __launch_bounds__(256) void k_cscanA(int* __restrict__ P,
                                                int* __restrict__ bintotal) {
    __shared__ int sh[NC];
    const int b = blockIdx.x;
    const int t = threadIdx.x;
    const int v = P[b * NC + t];
    sh[t] = v;
    __syncthreads();
    for (int off = 1; off < NC; off <<= 1) {
        int u = (t >= off) ? sh[t - off] : 0;
        __syncthreads();
        sh[t] += u;
        __syncthreads();
    }
    P[b * NC + t] = sh[t] - v;            // exclusive prefix within bin
    if (t == NC - 1) bintotal[b] = sh[t];
}

__global__ __launch_bounds__(1024) void k_cscanB(const int* __restrict__ bintotal,
                                                 int* __restrict__ binbase) {
    __shared__ int sh[1024];
    const int t = threadIdx.x;
    const int v = (t < CB) ? bintotal[t] : 0;
    sh[t] = v;
    __syncthreads();
    for (int off = 1; off < 1024; off <<= 1) {
        int u = (t >= off) ? sh[t - off] : 0;
        __syncthreads();
        sh[t] += u;
        __syncthreads();
    }
    if (t < CB) binbase[t] = sh[t] - v;
    if (t == CB - 1) binbase[CB] = sh[t];    // = NE
}

__global__ __launch_bounds__(256) void k_cscatter(const int* __restrict__ dst,
                                                  const int* __restrict__ src,
                                                  const int* __restrict__ P,
                                                  const int* __restrict__ binbase,
                                                  int* __restrict__ skey,
                                                  int* __restrict__ sval) {
    __shared__ int cur[CB];
    const int c = blockIdx.x;
    const int t = threadIdx.x;
    for (int i = t; i < CB; i += 256) cur[i] = binbase[i] + P[i * NC + c];
    __syncthreads();
    const int base = c * EPC;
    for (int i = t; i < EPC; i += 256) {
        int d = dst[base + i];
        int pos = atomicAdd(&cur[d >> 7], 1);   // LDS atomic
        skey[pos] = d;
        sval[pos] = src[base + i];
    }
}

__global__ __launch_bounds__(256) void k_fine(const int* __restrict__ skey,
                                              const int* __restrict__ sval,
                                              const int* __restrict__ binbase,
                                              int* __restrict__ ptr,
                                              float* __restrict__ degin,
                                              int* __restrict__ esrc) {
    __shared__ int fh[128], fp[128], fcur[128];
    const int b = blockIdx.x;
    const int t = threadIdx.x;
    const int lo = binbase[b], hi = binbase[b + 1];
    if (t < 128) fh[t] = 0;
    __syncthreads();
    for (int i = lo + t; i < hi; i += 256)
        atomicAdd(&fh[skey[i] & 127], 1);
    __syncthreads();
    if (t < 128) fp[t] = fh[t];
    __syncthreads();
    for (int off = 1; off < 128; off <<= 1) {
        int u = (t < 128 && t >= off) ? fp[t - off] : 0;
        __syncthreads();
        if (t < 128) fp[t] += u;
        __syncthreads();
    }
    if (t < 128) {
        const int node = b * 128 + t;
        const int ex = fp[t] - fh[t];       // exclusive prefix within bin
        fcur[t] = ex;
        if (node < NN) {
            ptr[node] = lo + ex;
            degin[node] = (float)fh[t];
        } else if (node == NN) {
            ptr[NN] = lo + ex;
        }
    }
    __syncthreads();
    for (int i = lo + t; i < hi; i += 256) {
        int d = skey[i];
        int pos = atomicAdd(&fcur[d & 127], 1);   // LDS atomic
        esrc[lo + pos] = sval[i];
    }
}

// ======== src slice-histogram (deg_out, no global atomics) ========

__global__ __launch_bounds__(256) void k_shist(const int* __restrict__ src,
                                               int* __restrict__ SP /*[NSLICE][SCH][SLICESZ]*/) {
    __shared__ int hist[SLICESZ];
    const int s = blockIdx.x / SCH;
    const int c = blockIdx.x % SCH;
    const int t = threadIdx.x;
    const int lo = s * SLICESZ;
    for (int i = t; i < SLICESZ; i += 256) hist[i] = 0;
    __syncthreads();
    const int base = c * EPH;
    for (int i = t; i < EPH; i += 256) {
        int k = src[base + i] - lo;
        if ((unsigned)k < (unsigned)SLICESZ) atomicAdd(&hist[k], 1);
    }
    __syncthreads();
    int* out = SP + ((size_t)s * SCH + c) * SLICESZ;
    for (int i = t; i < SLICESZ; i += 256) out[i] = hist[i];
}

__global__ void k_smerge(const int* __restrict__ SP, float* __restrict__ degout) {
    int n = blockIdx.x * 256 + threadIdx.x;
    if (n >= NN) return;
    const int s = n / SLICESZ, k = n % SLICESZ;
    const int* col = SP + ((size_t)s * SCH) * SLICESZ + k;
    int sum = 0;
#pragma unroll
    for (int c = 0; c < SCH; ++c) sum += col[(size_t)c * SLICESZ];
    degout[n] = (float)sum;
}

// ---------------- Kernel 2: h(bf16) = (x * rsqrt(max(deg_out,1))) @ W via MFMA ----------------
__global__ __launch_bounds__(256) void k_gemm(const float* __restrict__ x,
                                              const float* __restrict__ degout,
                                              const ushort* __restrict__ WT,
                                              ushort* __restrict__ h) {
    __shared__ ushort Wl[D * WLD];   // 34.8 KB

    const int t = threadIdx.x;
    for (int s = t; s < 2048; s += 256) {
        int row = s >> 4, slot = s & 15;
        uint4 v = *reinterpret_cast<const uint4*>(WT + row * D + slot * 8);
        *reinterpret_cast<uint4*>(&Wl[row * WLD + slot * 8]) = v;
    }
    __syncthreads();

    const int wave = t >> 6;
    const int lane = t & 63;
    const int m16  = lane & 15;
    const int kq   = lane >> 4;
    const int row  = blockIdx.x * 64 + wave * 16 + m16;
    const int rc   = row < NN ? row : NN - 1;

    const float nrm = rsqrtf(fmaxf(degout[rc], 1.0f));

    bf16x8 afrag[4];
    const float* xr = x + (size_t)rc * D + kq * 8;
#pragma unroll
    for (int kt = 0; kt < 4; ++kt) {
        f32x4 lo = *reinterpret_cast<const f32x4*>(xr + kt * 32);
        f32x4 hi = *reinterpret_cast<const f32x4*>(xr + kt * 32 + 4);
        union { bf16x8 v; ushort u[8]; } af;
#pragma unroll
        for (int j = 0; j < 4; ++j) {
            af.u[j]     = f2bf(lo[j] * nrm);
            af.u[4 + j] = f2bf(hi[j] * nrm);
        }
        afrag[kt] = af.v;
    }

    f32x4 acc[8];
#pragma unroll
    for (int nt = 0; nt < 8; ++nt) acc[nt] = (f32x4)(0.0f);

#pragma unroll
    for (int kt = 0; kt < 4; ++kt) {
#pragma unroll
        for (int nt = 0; nt < 8; ++nt) {
            int n = nt * 16 + m16;
            const bf16x8 bfrag = *reinterpret_cast<const bf16x8*>(
                &Wl[n * WLD + kt * 32 + kq * 8]);
            acc[nt] = __builtin_amdgcn_mfma_f32_16x16x32_bf16(afrag[kt], bfrag, acc[nt], 0, 0, 0);
        }
    }

    const int orow = blockIdx.x * 64 + wave * 16 + kq * 4;
#pragma unroll
    for (int nt = 0; nt < 8; ++nt) {
#pragma unroll
        for (int r = 0; r < 4; ++r) {
            int rr = orow + r;
            if (rr < NN) h[(size_t)rr * D + nt * 16 + m16] = f2bf(acc[nt][r]);
        }
    }
}

// ---------------- Kernel 3c: gather-sum, 16 lanes/edge x 16B, 8 edges in flight ----------------
// h2 output is bf16 (packed pairs).
__global__ __launch_bounds__(256) void k_agg(const ushort* __restrict__ h,
                                             const int* __restrict__ ptr,
                                             const int* __restrict__ esrc,
                                             const float* __restrict__ degin,
                                             const float* __restrict__ b,
                                             ushort* __restrict__ h2) {
    const int node = blockIdx.x * 4 + (threadIdx.x >> 6);
    const int lane = threadIdx.x & 63;
    if (node >= NN) return;
    const int s0 = ptr[node];
    const int s1 = ptr[node + 1];
    const int eg = lane >> 4;          // edge slot 0..3
    const int cb = (lane & 15) * 8;    // column block: 8 bf16 = 16 B

    float acc[8];
#pragma unroll
    for (int j = 0; j < 8; ++j) acc[j] = 0.0f;

    for (int i = s0; i < s1; i += 8) {
        const int i0 = i + eg;
        const int i1 = i0 + 4;
        uint4 v0, v1;
        const bool p0 = i0 < s1;
        const bool p1 = i1 < s1;
        if (p0) v0 = *reinterpret_cast<const uint4*>(h + (size_t)esrc[i0] * D + cb);
        if (p1) v1 = *reinterpret_cast<const uint4*>(h + (size_t)esrc[i1] * D + cb);
        if (p0) {
            acc[0] += bflo(v0.x); acc[1] += bfhi(v0.x);
            acc[2] += bflo(v0.y); acc[3] += bfhi(v0.y);
            acc[4] += bflo(v0.z); acc[5] += bfhi(v0.z);
            acc[6] += bflo(v0.w); acc[7] += bfhi(v0.w);
        }
        if (p1) {
            acc[0] += bflo(v1.x); acc[1] += bfhi(v1.x);
            acc[2] += bflo(v1.y); acc[3] += bfhi(v1.y);
            acc[4] += bflo(v1.z); acc[5] += bfhi(v1.z);
            acc[6] += bflo(v1.w); acc[7] += bfhi(v1.w);
        }
    }
    // fold the 4 edge-slot groups: lanes (l, l^16, l^32, l^48) share a column block
#pragma unroll
    for (int j = 0; j < 8; ++j) {
        acc[j] += __shfl_xor(acc[j], 16, 64);
        acc[j] += __shfl_xor(acc[j], 32, 64);
    }
    if (eg == 0) {
        const float nrm = rsqrtf(fmaxf(degin[node], 1.0f));
        uint4 o;
        unsigned w[4];
#pragma unroll
        for (int m = 0; m < 4; ++m) {
            float e0 = acc[2 * m]     * nrm + b[cb + 2 * m];
            float e1 = acc[2 * m + 1] * nrm + b[cb + 2 * m + 1];
            w[m] = (unsigned)f2bf(e0) | ((unsigned)f2bf(e1) << 16);
        }
        o.x = w[0]; o.y = w[1]; o.z = w[2]; o.w = w[3];
        *reinterpret_cast<uint4*>(h2 + (size_t)node * D + cb) = o;
    }
}

// ---------------- Kernel 4: column sums / sumsq of bf16 h2 ----------------
__global__ __launch_bounds__(256) void k_stats(const unsigned* __restrict__ h2u,
                                               float* __restrict__ stats) {
    __shared__ float red[4][256];
    const int t = threadIdx.x;
    float s1lo = 0.f, s1hi = 0.f, s2lo = 0.f, s2hi = 0.f;
    const int total = NN * (D / 2);
    const int stride = gridDim.x * 256;
    for (int i = blockIdx.x * 256 + t; i < total; i += stride) {
        unsigned v = h2u[i];
        float lo = bflo(v), hi = bfhi(v);
        s1lo += lo; s1hi += hi;
        s2lo += lo * lo; s2hi += hi * hi;
    }
    red[0][t] = s1lo; red[1][t] = s1hi; red[2][t] = s2lo; red[3][t] = s2hi;
    __syncthreads();
    if (t < 64) {
        const int c = t * 2;   // column pair (i&63)*2
        float a0 = red[0][t] + red[0][t + 64] + red[0][t + 128] + red[0][t + 192];
        float a1 = red[1][t] + red[1][t + 64] + red[1][t + 128] + red[1][t + 192];
        float q0 = red[2][t] + red[2][t + 64] + red[2][t + 128] + red[2][t + 192];
        float q1 = red[3][t] + red[3][t + 64] + red[3][t + 128] + red[3][t + 192];
        atomicAdd(&stats[c], a0);
        atomicAdd(&stats[c + 1], a1);
        atomicAdd(&stats[128 + c], q0);
        atomicAdd(&stats[128 + c + 1], q1);
    }
}

// ---------------- Kernel 5: BN + ReLU + residual (h2 bf16 -> out f32) ----------------
__global__ void k_final(const unsigned* __restrict__ h2u, const float* __restrict__ x,
                        const float* __restrict__ gamma, const float* __restrict__ beta,
                        const float* __restrict__ stats, float* __restrict__ out) {
    const int i = blockIdx.x * 256 + threadIdx.x;   // over NN*64 uints
    const int total = NN * (D / 2);
    if (i >= total) return;
    const int c = (i & 63) * 2;
    const float inv_n = 1.0f / (float)NN;
    float mean0 = stats[c] * inv_n;
    float mean1 = stats[c + 1] * inv_n;
    float var0  = stats[128 + c] * inv_n - mean0 * mean0;
    float var1  = stats[128 + c + 1] * inv_n - mean1 * mean1;
    unsigned v = h2u[i];
    float2 xv = *reinterpret_cast<const float2*>(x + (size_t)i * 2);
    float o0 = (bflo(v) - mean0) * rsqrtf(var0 + BN_EPS) * gamma[c] + beta[c];
    float o1 = (bfhi(v) - mean1) * rsqrtf(var1 + BN_EPS) * gamma[c + 1] + beta[c + 1];
    o0 = fmaxf(o0, 0.0f) + xv.x;
    o1 = fmaxf(o1, 0.0f) + xv.y;
    float2 o; o.x = o0; o.y = o1;
    *reinterpret_cast<float2*>(out + (size_t)i * 2) = o;
}

extern "C" void kernel_launch(void* const* d_in, const int* in_sizes, int n_in,
                              void* d_out, int out_size, void* d_ws, size_t ws_size,
                              hipStream_t stream) {
    const float* x     = (const float*)d_in[0];
    const int*   src   = (const int*)d_in[1];
    const int*   dst   = (const int*)d_in[2];
    const float* W     = (const float*)d_in[3];
    const float* b     = (const float*)d_in[4];
    const float* gamma = (const float*)d_in[5];
    const float* beta  = (const float*)d_in[6];
    float* out = (float*)d_out;

    // Workspace layout (h2 region kept at NN*D floats for overlays; h2 itself bf16)
    float* ws     = (float*)d_ws;
    ushort* h2    = (ushort*)ws;                      // NN*D bf16 (written by k_agg)
    float* degout = ws + (size_t)NN * D;              // NN
    float* degin  = degout + NN;                      // NN
    float* stats  = degin + NN;                       // 256 -- zeroed
    int*   ptr    = (int*)(stats + 256);              // NN+1
    int*   esrc   = ptr + (NN + 1);                   // NE
    ushort* WT    = (ushort*)(esrc + NE);             // 128*128 bf16

    // Overlays in the h2 region (all dead before k_agg writes h2): ~26.5 MB < 51.2 MB
    int* skey     = (int*)ws;                         // NE
    int* sval     = skey + NE;                        // NE
    int* SP       = sval + NE;                        // NSLICE*SCH*SLICESZ
    int* P        = SP + (size_t)NSLICE * SCH * SLICESZ;  // CB*NC
    int* bintotal = P + (size_t)CB * NC;              // CB
    int* binbase  = bintotal + CB;                    // CB+1

    // h (bf16) lives in d_out (overwritten by k_final at the end)
    ushort* h = (ushort*)d_out;

    hipMemsetAsync(stats, 0, 256 * sizeof(float), stream);

    k_wcast<<<64, 256, 0, stream>>>(W, WT);
    // dst counting sort -> CSR (esrc, ptr, degin)
    k_ccount<<<NC, 256, 0, stream>>>(dst, P);
    k_cscanA<<<CB, 256, 0, stream>>>(P, bintotal);
    k_cscanB<<<1, 1024, 0, stream>>>(bintotal, binbase);
    k_cscatter<<<NC, 256, 0, stream>>>(dst, src, P, binbase, skey, sval);
    // src slice histogram -> degout
    k_shist<<<NSLICE * SCH, 256, 0, stream>>>(src, SP);
    k_smerge<<<(NN + 255) / 256, 256, 0, stream>>>(SP, degout);
    k_gemm<<<(NN + 63) / 64, 256, 0, stream>>>(x, degout, WT, h);
    k_fine<<<CB, 256, 0, stream>>>(skey, sval, binbase, ptr, degin, esrc);
    k_agg<<<(NN + 3) / 4, 256, 0, stream>>>(h, ptr, esrc, degin, b, h2);
    k_stats<<<1024, 256, 0, stream>>>((const unsigned*)h2, stats);
    k_final<<<(NN * (D / 2) + 255) / 256, 256, 0, stream>>>((const unsigned*)h2, x, gamma, beta, stats, out);
}

// Round 9
// 277.305 us; speedup vs baseline: 3.9822x; 1.0756x over previous
//
#include <hip/hip_runtime.h>
#include <hip/hip_bf16.h>

#define NN 100000
#define NE 1600000
#define D  128
#define BN_EPS 1e-5f

// counting-sort geometry (dst path)
#define CB  782                 // coarse bins = ceil(NN/128), bin = 128 nodes
#define NC  256                 // chunks
#define EPC (NE / NC)           // 6250 edges per chunk
// slice-histogram geometry (src path)
#define NSLICE  7
#define SLICESZ 15400           // 7*15400 = 107800 >= NN; 61.6 KB LDS
#define SCH     32
#define EPH (NE / SCH)          // 50000

typedef __attribute__((ext_vector_type(8))) short bf16x8;
typedef __attribute__((ext_vector_type(4))) float f32x4;

#define WLD 136   // padded row stride (ushorts) for W^T in LDS: 2-way banks only

static __device__ __forceinline__ ushort f2bf(float f) {
    __hip_bfloat16 b = __float2bfloat16(f);
    return *reinterpret_cast<ushort*>(&b);
}
static __device__ __forceinline__ float bflo(unsigned v) {
    return __uint_as_float((v & 0xffffu) << 16);
}
static __device__ __forceinline__ float bfhi(unsigned v) {
    return __uint_as_float(v & 0xffff0000u);
}

// ---------------- Kernel 0: W^T cast to bf16 ----------------
__global__ void k_wcast(const float* __restrict__ W, ushort* __restrict__ WT) {
    int i = blockIdx.x * 256 + threadIdx.x;   // 16384
    int n = i >> 7, k = i & 127;
    WT[i] = f2bf(W[k * D + n]);               // WT[n][k] = W[k][n]
}

// ======== dst counting-sort pipeline (no global atomics) ========

__global__ __launch_bounds__(256) void k_ccount(const int* __restrict__ dst,
                                                int* __restrict__ P /*[CB][NC]*/) {
    __shared__ int hist[CB];
    const int c = blockIdx.x;
    const int t = threadIdx.x;
    for (int i = t; i < CB; i += 256) hist[i] = 0;
    __syncthreads();
    const int base = c * EPC;
    for (int i = t; i < EPC; i += 256)
        atomicAdd(&hist[dst[base + i] >> 7], 1);
    __syncthreads();
    for (int i = t; i < CB; i += 256) P[i * NC + c] = hist[i];
}

__global__ __launch_bounds__(256) void k_cscanA(int* __restrict__ P,
                                                int* __restrict__ bintotal) {
    __shared__ int sh[NC];
    const int b = blockIdx.x;
    const int t = threadIdx.x;
    const int v = P[b * NC + t];
    sh[t] = v;
    __syncthreads();
    for (int off = 1; off < NC; off <<= 1) {
        int u = (t >= off) ? sh[t - off] : 0;
        __syncthreads();
        sh[t] += u;
        __syncthreads();
    }
    P[b * NC + t] = sh[t] - v;            // exclusive prefix within bin
    if (t == NC - 1) bintotal[b] = sh[t];
}

__global__ __launch_bounds__(1024) void k_cscanB(const int* __restrict__ bintotal,
                                                 int* __restrict__ binbase) {
    __shared__ int sh[1024];
    const int t = threadIdx.x;
    const int v = (t < CB) ? bintotal[t] : 0;
    sh[t] = v;
    __syncthreads();
    for (int off = 1; off < 1024; off <<= 1) {
        int u = (t >= off) ? sh[t - off] : 0;
        __syncthreads();
        sh[t] += u;
        __syncthreads();
    }
    if (t < CB) binbase[t] = sh[t] - v;
    if (t == CB - 1) binbase[CB] = sh[t];    // = NE
}

// Phase C: scatter packed edge (src | (dst&127)<<17) into coarse-bin order
__global__ __launch_bounds__(256) void k_cscatter(const int* __restrict__ dst,
                                                  const int* __restrict__ src,
                                                  const int* __restrict__ P,
                                                  const int* __restrict__ binbase,
                                                  int* __restrict__ sedge) {
    __shared__ int cur[CB];
    const int c = blockIdx.x;
    const int t = threadIdx.x;
    for (int i = t; i < CB; i += 256) cur[i] = binbase[i] + P[i * NC + c];
    __syncthreads();
    const int base = c * EPC;
    for (int i = t; i < EPC; i += 256) {
        int d = dst[base + i];
        int pos = atomicAdd(&cur[d >> 7], 1);   // LDS atomic
        sedge[pos] = src[base + i] | ((d & 127) << 17);
    }
}

// Phase D: per-coarse-bin fine CSR from packed edges. Emits ptr, esrc.
__global__ __launch_bounds__(256) void k_fine(const int* __restrict__ sedge,
                                              const int* __restrict__ binbase,
                                              int* __restrict__ ptr,
                                              int* __restrict__ esrc) {
    __shared__ int fh[128], fp[128], fcur[128];
    const int b = blockIdx.x;
    const int t = threadIdx.x;
    const int lo = binbase[b], hi = binbase[b + 1];
    if (t < 128) fh[t] = 0;
    __syncthreads();
    for (int i = lo + t; i < hi; i += 256)
        atomicAdd(&fh[(unsigned)sedge[i] >> 17], 1);
    __syncthreads();
    if (t < 128) fp[t] = fh[t];
    __syncthreads();
    for (int off = 1; off < 128; off <<= 1) {
        int u = (t < 128 && t >= off) ? fp[t - off] : 0;
        __syncthreads();
        if (t < 128) fp[t] += u;
        __syncthreads();
    }
    if (t < 128) {
        const int node = b * 128 + t;
        const int ex = fp[t] - fh[t];       // exclusive prefix within bin
        fcur[t] = ex;
        if (node < NN) {
            ptr[node] = lo + ex;
        } else if (node == NN) {
            ptr[NN] = lo + ex;              // = NE (trailing nodes empty)
        }
    }
    __syncthreads();
    for (int i = lo + t; i < hi; i += 256) {
        unsigned v = (unsigned)sedge[i];
        int pos = atomicAdd(&fcur[v >> 17], 1);   // LDS atomic
        esrc[lo + pos] = v & 0x1FFFF;
    }
}

// ======== src slice-histogram (deg_out, no global atomics) ========

__global__ __launch_bounds__(256) void k_shist(const int* __restrict__ src,
                                               int* __restrict__ SP /*[NSLICE][SCH][SLICESZ]*/) {
    __shared__ int hist[SLICESZ];
    const int s = blockIdx.x / SCH;
    const int c = blockIdx.x % SCH;
    const int t = threadIdx.x;
    const int lo = s * SLICESZ;
    for (int i = t; i < SLICESZ; i += 256) hist[i] = 0;
    __syncthreads();
    const int base = c * EPH;
    for (int i = t; i < EPH; i += 256) {
        int k = src[base + i] - lo;
        if ((unsigned)k < (unsigned)SLICESZ) atomicAdd(&hist[k], 1);
    }
    __syncthreads();
    int* out = SP + ((size_t)s * SCH + c) * SLICESZ;
    for (int i = t; i < SLICESZ; i += 256) out[i] = hist[i];
}

__global__ void k_smerge(const int* __restrict__ SP, float* __restrict__ degout) {
    int n = blockIdx.x * 256 + threadIdx.x;
    if (n >= NN) return;
    const int s = n / SLICESZ, k = n % SLICESZ;
    const int* col = SP + ((size_t)s * SCH) * SLICESZ + k;
    int sum = 0;
#pragma unroll
    for (int c = 0; c < SCH; ++c) sum += col[(size_t)c * SLICESZ];
    degout[n] = (float)sum;
}

// ---------------- Kernel 2: h(bf16) = (x * rsqrt(max(deg_out,1))) @ W via MFMA ----------------
__global__ __launch_bounds__(256) void k_gemm(const float* __restrict__ x,
                                              const float* __restrict__ degout,
                                              const ushort* __restrict__ WT,
                                              ushort* __restrict__ h) {
    __shared__ ushort Wl[D * WLD];   // 34.8 KB

    const int t = threadIdx.x;
    for (int s = t; s < 2048; s += 256) {
        int row = s >> 4, slot = s & 15;
        uint4 v = *reinterpret_cast<const uint4*>(WT + row * D + slot * 8);
        *reinterpret_cast<uint4*>(&Wl[row * WLD + slot * 8]) = v;
    }
    __syncthreads();

    const int wave = t >> 6;
    const int lane = t & 63;
    const int m16  = lane & 15;
    const int kq   = lane >> 4;
    const int row  = blockIdx.x * 64 + wave * 16 + m16;
    const int rc   = row < NN ? row : NN - 1;

    const float nrm = rsqrtf(fmaxf(degout[rc], 1.0f));

    bf16x8 afrag[4];
    const float* xr = x + (size_t)rc * D + kq * 8;
#pragma unroll
    for (int kt = 0; kt < 4; ++kt) {
        f32x4 lo = *reinterpret_cast<const f32x4*>(xr + kt * 32);
        f32x4 hi = *reinterpret_cast<const f32x4*>(xr + kt * 32 + 4);
        union { bf16x8 v; ushort u[8]; } af;
#pragma unroll
        for (int j = 0; j < 4; ++j) {
            af.u[j]     = f2bf(lo[j] * nrm);
            af.u[4 + j] = f2bf(hi[j] * nrm);
        }
        afrag[kt] = af.v;
    }

    f32x4 acc[8];
#pragma unroll
    for (int nt = 0; nt < 8; ++nt) acc[nt] = (f32x4)(0.0f);

#pragma unroll
    for (int kt = 0; kt < 4; ++kt) {
#pragma unroll
        for (int nt = 0; nt < 8; ++nt) {
            int n = nt * 16 + m16;
            const bf16x8 bfrag = *reinterpret_cast<const bf16x8*>(
                &Wl[n * WLD + kt * 32 + kq * 8]);
            acc[nt] = __builtin_amdgcn_mfma_f32_16x16x32_bf16(afrag[kt], bfrag, acc[nt], 0, 0, 0);
        }
    }

    const int orow = blockIdx.x * 64 + wave * 16 + kq * 4;
#pragma unroll
    for (int nt = 0; nt < 8; ++nt) {
#pragma unroll
        for (int r = 0; r < 4; ++r) {
            int rr = orow + r;
            if (rr < NN) h[(size_t)rr * D + nt * 16 + m16] = f2bf(acc[nt][r]);
        }
    }
}

// ---------------- Kernel 3c: gather-sum, 16 lanes/edge x 16B, 16 edges in flight ----------------
__global__ __launch_bounds__(256) void k_agg(const ushort* __restrict__ h,
                                             const int* __restrict__ ptr,
                                             const int* __restrict__ esrc,
                                             const float* __restrict__ b,
                                             ushort* __restrict__ h2) {
    const int node = blockIdx.x * 4 + (threadIdx.x >> 6);
    const int lane = threadIdx.x & 63;
    if (node >= NN) return;
    const int s0 = ptr[node];
    const int s1 = ptr[node + 1];
    const int eg = lane >> 4;          // edge slot 0..3
    const int cb = (lane & 15) * 8;    // column block: 8 bf16 = 16 B

    float acc[8];
#pragma unroll
    for (int j = 0; j < 8; ++j) acc[j] = 0.0f;

    for (int i = s0; i < s1; i += 16) {
        int  idx[4];
        bool p[4];
        uint4 v[4];
#pragma unroll
        for (int u = 0; u < 4; ++u) {
            int ii = i + eg + 4 * u;
            p[u] = ii < s1;
            if (p[u]) idx[u] = esrc[ii];
        }
#pragma unroll
        for (int u = 0; u < 4; ++u)
            if (p[u]) v[u] = *reinterpret_cast<const uint4*>(h + (size_t)idx[u] * D + cb);
#pragma unroll
        for (int u = 0; u < 4; ++u) {
            if (p[u]) {
                acc[0] += bflo(v[u].x); acc[1] += bfhi(v[u].x);
                acc[2] += bflo(v[u].y); acc[3] += bfhi(v[u].y);
                acc[4] += bflo(v[u].z); acc[5] += bfhi(v[u].z);
                acc[6] += bflo(v[u].w); acc[7] += bfhi(v[u].w);
            }
        }
    }
    // fold the 4 edge-slot groups: lanes (l, l^16, l^32, l^48) share a column block
#pragma unroll
    for (int j = 0; j < 8; ++j) {
        acc[j] += __shfl_xor(acc[j], 16, 64);
        acc[j] += __shfl_xor(acc[j], 32, 64);
    }
    if (eg == 0) {
        const float nrm = rsqrtf(fmaxf((float)(s1 - s0), 1.0f));
        uint4 o;
        unsigned w[4];
#pragma unroll
        for (int m = 0; m < 4; ++m) {
            float e0 = acc[2 * m]     * nrm + b[cb + 2 * m];
            float e1 = acc[2 * m + 1] * nrm + b[cb + 2 * m + 1];
            w[m] = (unsigned)f2bf(e0) | ((unsigned)f2bf(e1) << 16);
        }
        o.x = w[0]; o.y = w[1]; o.z = w[2]; o.w = w[3];
        *reinterpret_cast<uint4*>(h2 + (size_t)node * D + cb) = o;
    }
}

// ---------------- Kernel 4: column sums / sumsq of bf16 h2 ----------------
__global__ __launch_bounds__(256) void k_stats(const unsigned* __restrict__ h2u,
                                               float* __restrict__ stats) {
    __shared__ float red[4][256];
    const int t = threadIdx.x;
    float s1lo = 0.f, s1hi = 0.f, s2lo = 0.f, s2hi = 0.f;
    const int total = NN * (D / 2);
    const int stride = gridDim.x * 256;
    for (int i = blockIdx.x * 256 + t; i < total; i += stride) {
        unsigned v = h2u[i];
        float lo = bflo(v), hi = bfhi(v);
        s1lo += lo; s1hi += hi;
        s2lo += lo * lo; s2hi += hi * hi;
    }
    red[0][t] = s1lo; red[1][t] = s1hi; red[2][t] = s2lo; red[3][t] = s2hi;
    __syncthreads();
    if (t < 64) {
        const int c = t * 2;   // column pair (i&63)*2
        float a0 = red[0][t] + red[0][t + 64] + red[0][t + 128] + red[0][t + 192];
        float a1 = red[1][t] + red[1][t + 64] + red[1][t + 128] + red[1][t + 192];
        float q0 = red[2][t] + red[2][t + 64] + red[2][t + 128] + red[2][t + 192];
        float q1 = red[3][t] + red[3][t + 64] + red[3][t + 128] + red[3][t + 192];
        atomicAdd(&stats[c], a0);
        atomicAdd(&stats[c + 1], a1);
        atomicAdd(&stats[128 + c], q0);
        atomicAdd(&stats[128 + c + 1], q1);
    }
}

// ---------------- Kernel 5: BN + ReLU + residual, 16B vectorized ----------------
__global__ void k_final(const uint2* __restrict__ h2v, const float4* __restrict__ xv,
                        const float* __restrict__ gamma, const float* __restrict__ beta,
                        const float* __restrict__ stats, float4* __restrict__ outv) {
    const int i = blockIdx.x * 256 + threadIdx.x;   // over NN*32 chunks of 4 cols
    const int total = NN * (D / 4);
    if (i >= total) return;
    const int c = (i & 31) * 4;
    const float inv_n = 1.0f / (float)NN;
    uint2 v = h2v[i];
    float4 xx = xv[i];
    float hv[4] = { bflo(v.x), bfhi(v.x), bflo(v.y), bfhi(v.y) };
    float xr[4] = { xx.x, xx.y, xx.z, xx.w };
    float o[4];
#pragma unroll
    for (int m = 0; m < 4; ++m) {
        float mean = stats[c + m] * inv_n;
        float var  = stats[128 + c + m] * inv_n - mean * mean;
        float t = (hv[m] - mean) * rsqrtf(var + BN_EPS) * gamma[c + m] + beta[c + m];
        o[m] = fmaxf(t, 0.0f) + xr[m];
    }
    float4 ov; ov.x = o[0]; ov.y = o[1]; ov.z = o[2]; ov.w = o[3];
    outv[i] = ov;
}

extern "C" void kernel_launch(void* const* d_in, const int* in_sizes, int n_in,
                              void* d_out, int out_size, void* d_ws, size_t ws_size,
                              hipStream_t stream) {
    const float* x     = (const float*)d_in[0];
    const int*   src   = (const int*)d_in[1];
    const int*   dst   = (const int*)d_in[2];
    const float* W     = (const float*)d_in[3];
    const float* b     = (const float*)d_in[4];
    const float* gamma = (const float*)d_in[5];
    const float* beta  = (const float*)d_in[6];
    float* out = (float*)d_out;

    // Workspace layout (first NN*D floats reserved for h2/overlays)
    float* ws     = (float*)d_ws;
    ushort* h2    = (ushort*)ws;                      // NN*D bf16 (written by k_agg)
    float* degout = ws + (size_t)NN * D;              // NN
    float* stats  = degout + NN;                      // 256 -- zeroed
    int*   ptr    = (int*)(stats + 256);              // NN+1
    int*   esrc   = ptr + (NN + 1);                   // NE
    ushort* WT    = (ushort*)(esrc + NE);             // 128*128 bf16

    // Overlays in the h2 region (all dead before k_agg writes h2): ~21 MB < 51.2 MB
    int* sedge    = (int*)ws;                         // NE (packed src | (dst&127)<<17)
    int* SP       = sedge + NE;                       // NSLICE*SCH*SLICESZ
    int* P        = SP + (size_t)NSLICE * SCH * SLICESZ;  // CB*NC
    int* bintotal = P + (size_t)CB * NC;              // CB
    int* binbase  = bintotal + CB;                    // CB+1

    // h (bf16) lives in d_out (overwritten by k_final at the end)
    ushort* h = (ushort*)d_out;

    hipMemsetAsync(stats, 0, 256 * sizeof(float), stream);

    k_wcast<<<64, 256, 0, stream>>>(W, WT);
    // dst counting sort -> CSR (esrc, ptr)
    k_ccount<<<NC, 256, 0, stream>>>(dst, P);
    k_cscanA<<<CB, 256, 0, stream>>>(P, bintotal);
    k_cscanB<<<1, 1024, 0, stream>>>(bintotal, binbase);
    k_cscatter<<<NC, 256, 0, stream>>>(dst, src, P, binbase, sedge);
    // src slice histogram -> degout
    k_shist<<<NSLICE * SCH, 256, 0, stream>>>(src, SP);
    k_smerge<<<(NN + 255) / 256, 256, 0, stream>>>(SP, degout);
    k_gemm<<<(NN + 63) / 64, 256, 0, stream>>>(x, degout, WT, h);
    k_fine<<<CB, 256, 0, stream>>>(sedge, binbase, ptr, esrc);
    k_agg<<<(NN + 3) / 4, 256, 0, stream>>>(h, ptr, esrc, b, h2);
    k_stats<<<1024, 256, 0, stream>>>((const unsigned*)h2, stats);
    k_final<<<(NN * (D / 4) + 255) / 256, 256, 0, stream>>>((const uint2*)h2, (const float4*)x,
                                                            gamma, beta, stats, (float4*)out);
}